// Round 2
// baseline (704.220 us; speedup 1.0000x reference)
//
#include <hip/hip_runtime.h>
#include <hip/hip_bf16.h>
#include <hip/hip_fp16.h>
#include <math.h>

// ---------------------------------------------------------------------------
// GAT (3 layers, heads=4/4/1, hid=32) + final linear, fp32 compute.
// R13 == R12 resubmit (R12 bench was an infra failure, no measurement).
// R12: fused gather kernels are latency-bound (R11 counters: VALU 36%, HBM 39%,
//      occ 43%, nothing saturated; effective gather BW only ~4.5 TB/s vs 435 MB
//      demand). Double edge-chunk 8 -> 16: each lane owns 2 edges, softmax
//      shuffle/exp chain runs once per 16 edges, 16 gathers in flight between
//      sync points. Applied to both f16 (layers 0/1) and fp32 (layer 2) fused
//      kernels. Everything else unchanged from R11.
// ---------------------------------------------------------------------------

#define NEG_SLOPE 0.2f

// ---------------- CSR build ----------------

__global__ void zero1_kernel(int* __restrict__ a, int n) {
    int i = blockIdx.x * blockDim.x + threadIdx.x;
    if (i < n) a[i] = 0;
}

__global__ void count_rank_kernel(const int* __restrict__ ei, int eraw, int n,
                                  int* __restrict__ deg, int* __restrict__ rank) {
    int i = blockIdx.x * blockDim.x + threadIdx.x;
    int etot = eraw + n;
    if (i >= etot) return;
    int dst = (i < eraw) ? ei[eraw + i] : (i - eraw);
    rank[i] = atomicAdd(&deg[dst], 1);
}

__global__ __launch_bounds__(1024)
void scan_local_kernel(const int* __restrict__ deg, int* __restrict__ rowptr,
                       int* __restrict__ bsum, int n) {
    __shared__ int buf[1024];
    int tid = threadIdx.x;
    int i = blockIdx.x * 1024 + tid;
    int v = (i < n) ? deg[i] : 0;
    buf[tid] = v;
    __syncthreads();
    for (int off = 1; off < 1024; off <<= 1) {
        int t = (tid >= off) ? buf[tid - off] : 0;
        __syncthreads();
        buf[tid] += t;
        __syncthreads();
    }
    if (i < n) rowptr[i] = buf[tid] - v;
    if (tid == 1023) bsum[blockIdx.x] = buf[1023];
}

__global__ __launch_bounds__(128)
void scan_sums_kernel(const int* __restrict__ bsum, int* __restrict__ boffs, int nb) {
    __shared__ int buf[128];
    int tid = threadIdx.x;
    int v = (tid < nb) ? bsum[tid] : 0;
    buf[tid] = v;
    __syncthreads();
    for (int off = 1; off < 128; off <<= 1) {
        int t = (tid >= off) ? buf[tid - off] : 0;
        __syncthreads();
        buf[tid] += t;
        __syncthreads();
    }
    if (tid < nb) boffs[tid] = buf[tid] - v;
}

__global__ void scan_add_kernel(int* __restrict__ rowptr, const int* __restrict__ boffs,
                                int n, int etot) {
    int i = blockIdx.x * blockDim.x + threadIdx.x;
    if (i < n) rowptr[i] += boffs[i >> 10];
    if (i == 0) rowptr[n] = etot;
}

__global__ void scatter2_kernel(const int* __restrict__ ei, const int* __restrict__ rank,
                                int eraw, int n, const int* __restrict__ rowptr,
                                int* __restrict__ csr_src) {
    int i = blockIdx.x * blockDim.x + threadIdx.x;
    int etot = eraw + n;
    if (i >= etot) return;
    int src, dst;
    if (i < eraw) { src = ei[i]; dst = ei[eraw + i]; }
    else          { src = i - eraw; dst = src; }
    csr_src[rowptr[dst] + rank[i]] = src;
}

// ---------------- register-tiled GEMM, fp16 output -------------------------
// H16[n,128] = X[n,128] @ W[128,128], stored as __half. n % 32 == 0.

struct h4pack { __half2 a, b; };   // 4 halves = 8 B

__global__ __launch_bounds__(256)
void gemm_rt_f16_kernel(const float* __restrict__ X, const float* __restrict__ W,
                        __half* __restrict__ H, int n) {
    __shared__ float xsT[128][36];
    int t = threadIdx.x;
    int base = blockIdx.x * 32;
    {
        int r  = t >> 3;
        int k0 = (t & 7) << 4;
        const float4* xp = (const float4*)(X + (size_t)(base + r) * 128 + k0);
        float4 a = xp[0], b = xp[1], c = xp[2], d = xp[3];
        xsT[k0 +  0][r] = a.x; xsT[k0 +  1][r] = a.y; xsT[k0 +  2][r] = a.z; xsT[k0 +  3][r] = a.w;
        xsT[k0 +  4][r] = b.x; xsT[k0 +  5][r] = b.y; xsT[k0 +  6][r] = b.z; xsT[k0 +  7][r] = b.w;
        xsT[k0 +  8][r] = c.x; xsT[k0 +  9][r] = c.y; xsT[k0 + 10][r] = c.z; xsT[k0 + 11][r] = c.w;
        xsT[k0 + 12][r] = d.x; xsT[k0 + 13][r] = d.y; xsT[k0 + 14][r] = d.z; xsT[k0 + 15][r] = d.w;
    }
    __syncthreads();

    int tx = t & 31;
    int ty = t >> 5;
    float4 acc0 = make_float4(0.f, 0.f, 0.f, 0.f);
    float4 acc1 = acc0, acc2 = acc0, acc3 = acc0;
    const float4* W4 = (const float4*)W;

#pragma unroll 4
    for (int k = 0; k < 128; k++) {
        float4 w  = W4[k * 32 + tx];
        float4 xv = *(const float4*)(&xsT[k][ty << 2]);
        acc0.x += xv.x * w.x; acc0.y += xv.x * w.y; acc0.z += xv.x * w.z; acc0.w += xv.x * w.w;
        acc1.x += xv.y * w.x; acc1.y += xv.y * w.y; acc1.z += xv.y * w.z; acc1.w += xv.y * w.w;
        acc2.x += xv.z * w.x; acc2.y += xv.z * w.y; acc2.z += xv.z * w.z; acc2.w += xv.z * w.w;
        acc3.x += xv.w * w.x; acc3.y += xv.w * w.y; acc3.z += xv.w * w.z; acc3.w += xv.w * w.w;
    }

    size_t row0 = (size_t)(base + (ty << 2));
    h4pack* hp = (h4pack*)(H + row0 * 128) + tx;      // row stride = 32 h4pack
    h4pack p;
    p.a = __floats2half2_rn(acc0.x, acc0.y); p.b = __floats2half2_rn(acc0.z, acc0.w);
    hp[0]  = p;
    p.a = __floats2half2_rn(acc1.x, acc1.y); p.b = __floats2half2_rn(acc1.z, acc1.w);
    hp[32] = p;
    p.a = __floats2half2_rn(acc2.x, acc2.y); p.b = __floats2half2_rn(acc2.z, acc2.w);
    hp[64] = p;
    p.a = __floats2half2_rn(acc3.x, acc3.y); p.b = __floats2half2_rn(acc3.z, acc3.w);
    hp[96] = p;
}

// ---------------- fallback GEMM (layer 2, OUTC=32, fp32) -------------------

template <int OUTC, int ROWS>
__global__ __launch_bounds__(128)
void gemm_kernel(const float* __restrict__ X, const float* __restrict__ W,
                 float* __restrict__ H, int n) {
    constexpr int GROUPS = 128 / OUTC;
    constexpr int RPT = ROWS / GROUPS;
    __shared__ float xs[ROWS][129];
    int base = blockIdx.x * ROWS;
    for (int i = threadIdx.x; i < ROWS * 128; i += 128) {
        int r = i >> 7, c = i & 127;
        int row = base + r;
        xs[r][c] = (row < n) ? X[(size_t)row * 128 + c] : 0.f;
    }
    __syncthreads();
    int col  = threadIdx.x % OUTC;
    int rsub = threadIdx.x / OUTC;
    float acc[RPT];
#pragma unroll
    for (int j = 0; j < RPT; j++) acc[j] = 0.f;
    for (int k = 0; k < 128; k++) {
        float w = W[k * OUTC + col];
#pragma unroll
        for (int j = 0; j < RPT; j++)
            acc[j] += xs[rsub + j * GROUPS][k] * w;
    }
#pragma unroll
    for (int j = 0; j < RPT; j++) {
        int row = base + rsub + j * GROUPS;
        if (row < n) H[(size_t)row * OUTC + col] = acc[j];
    }
}

// ---------------- attention coefficients (fp16 H) --------------------------

__global__ void attn_coef_f16_kernel(const __half* __restrict__ H,
                                     const float* __restrict__ a_s,
                                     const float* __restrict__ a_d,
                                     float* __restrict__ as_out,
                                     float* __restrict__ ad_out, int n) {
    int i = blockIdx.x * blockDim.x + threadIdx.x;
    if (i >= n * 4) return;
    int node = i >> 2, h = i & 3;
    const __half2* hp = (const __half2*)(H + (size_t)node * 128 + h * 32);
    float s = 0.f, d = 0.f;
#pragma unroll
    for (int c2 = 0; c2 < 16; c2++) {
        float2 v = __half22float2(hp[c2]);
        s += v.x * a_s[h * 32 + c2 * 2] + v.y * a_s[h * 32 + c2 * 2 + 1];
        d += v.x * a_d[h * 32 + c2 * 2] + v.y * a_d[h * 32 + c2 * 2 + 1];
    }
    as_out[i] = s;
    ad_out[i] = d;
}

// fp32 variant (layer 2)
template <int HEADS_, int C_>
__global__ void attn_coef_kernel(const float* __restrict__ H,
                                 const float* __restrict__ a_s,
                                 const float* __restrict__ a_d,
                                 float* __restrict__ as_out,
                                 float* __restrict__ ad_out, int n) {
    int i = blockIdx.x * blockDim.x + threadIdx.x;
    if (i >= n * HEADS_) return;
    int node = i / HEADS_, h = i % HEADS_;
    const float* hp = H + ((size_t)node * HEADS_ + h) * C_;
    float s = 0.f, d = 0.f;
#pragma unroll
    for (int c = 0; c < C_; c++) {
        float v = hp[c];
        s += v * a_s[h * C_ + c];
        d += v * a_d[h * C_ + c];
    }
    as_out[i] = s;
    ad_out[i] = d;
}

// ---------------- fused online-softmax aggregation, fp16 gathers -----------
// 4 heads, GS=32 lanes/node; lane tl covers channels 4tl..4tl+3 (8 B fp16).
// R12: 16-edge chunks; each lane owns edges eb+k8 (A-slot) and eb+8+k8
// (B-slot). Softmax reduction chain runs once per 16 edges; 16 independent
// gathers in flight between sync points.

__global__ __launch_bounds__(256)
void gat_fused_f16_kernel(const __half* __restrict__ Hm,
                          const float* __restrict__ as_,
                          const float* __restrict__ ad_,
                          const int* __restrict__ rowptr,
                          const int* __restrict__ csr,
                          const float* __restrict__ bias,
                          float* __restrict__ out, int n) {
    constexpr int GS = 32;
    int t = threadIdx.x;
    int node = blockIdx.x * 8 + (t >> 5);
    if (node >= n) return;
    int tl = t & 31;
    int h  = tl >> 3;
    int k8 = tl & 7;
    const uint2* H8 = (const uint2*)Hm;     // 8 B = 4 halves per lane
    int e0 = rowptr[node], e1 = rowptr[node + 1];
    float ad_d = ad_[(size_t)node * 4 + h];

    int  ceA  = e0 + k8;
    int  ceB  = e0 + 8 + k8;
    bool vA   = ceA < e1;
    bool vB   = ceB < e1;
    int  idxA = vA ? csr[ceA] : 0;
    int  idxB = vB ? csr[ceB] : 0;
    float asA = vA ? as_[(size_t)idxA * 4 + h] : 0.f;
    float asB = vB ? as_[(size_t)idxB * 4 + h] : 0.f;

    float m = -INFINITY, l = 0.f;
    float4 acc = make_float4(0.f, 0.f, 0.f, 0.f);

    for (int eb = e0; eb < e1; eb += 16) {
        // prefetch next chunk's indices + alpha_src
        int  neA   = eb + 16 + k8;
        int  neB   = eb + 24 + k8;
        bool nvA   = neA < e1;
        bool nvB   = neB < e1;
        int  nidxA = nvA ? csr[neA] : 0;
        int  nidxB = nvB ? csr[neB] : 0;
        float nasA = nvA ? as_[(size_t)nidxA * 4 + h] : 0.f;
        float nasB = nvB ? as_[(size_t)nidxB * 4 + h] : 0.f;

        float elA = asA + ad_d;
        elA = (elA > 0.f) ? elA : NEG_SLOPE * elA;
        elA = vA ? elA : -INFINITY;
        float elB = asB + ad_d;
        elB = (elB > 0.f) ? elB : NEG_SLOPE * elB;
        elB = vB ? elB : -INFINITY;

        float cm = fmaxf(elA, elB);
        cm = fmaxf(cm, __shfl_xor(cm, 1, 8));
        cm = fmaxf(cm, __shfl_xor(cm, 2, 8));
        cm = fmaxf(cm, __shfl_xor(cm, 4, 8));
        float m_new = fmaxf(m, cm);
        float scale = __expf(m - m_new);
        float pA = vA ? __expf(elA - m_new) : 0.f;
        float pB = vB ? __expf(elB - m_new) : 0.f;

        float ps = pA + pB;
        ps += __shfl_xor(ps, 1, 8);
        ps += __shfl_xor(ps, 2, 8);
        ps += __shfl_xor(ps, 4, 8);
        l = l * scale + ps;
        acc.x *= scale; acc.y *= scale; acc.z *= scale; acc.w *= scale;
        m = m_new;

        int cnt = e1 - eb; if (cnt > 16) cnt = 16;
        if (cnt == 16) {
#pragma unroll
            for (int j = 0; j < 8; j++) {
                int   srcA = __shfl(idxA, j, 8);
                int   srcB = __shfl(idxB, j, 8);
                float pjA  = __shfl(pA, j, 8);
                float pjB  = __shfl(pB, j, 8);
                uint2 uA = H8[(size_t)srcA * GS + tl];
                uint2 uB = H8[(size_t)srcB * GS + tl];
                float2 a01 = __half22float2(*(const __half2*)&uA.x);
                float2 a23 = __half22float2(*(const __half2*)&uA.y);
                float2 b01 = __half22float2(*(const __half2*)&uB.x);
                float2 b23 = __half22float2(*(const __half2*)&uB.y);
                acc.x += pjA * a01.x; acc.y += pjA * a01.y;
                acc.z += pjA * a23.x; acc.w += pjA * a23.y;
                acc.x += pjB * b01.x; acc.y += pjB * b01.y;
                acc.z += pjB * b23.x; acc.w += pjB * b23.y;
            }
        } else {
            int cA = (cnt < 8) ? cnt : 8;
            for (int j = 0; j < cA; j++) {
                int   src = __shfl(idxA, j, 8);
                float pj  = __shfl(pA, j, 8);
                uint2 u = H8[(size_t)src * GS + tl];
                float2 f01 = __half22float2(*(const __half2*)&u.x);
                float2 f23 = __half22float2(*(const __half2*)&u.y);
                acc.x += pj * f01.x; acc.y += pj * f01.y;
                acc.z += pj * f23.x; acc.w += pj * f23.y;
            }
            int cB = cnt - 8;
            for (int j = 0; j < cB; j++) {
                int   src = __shfl(idxB, j, 8);
                float pj  = __shfl(pB, j, 8);
                uint2 u = H8[(size_t)src * GS + tl];
                float2 f01 = __half22float2(*(const __half2*)&u.x);
                float2 f23 = __half22float2(*(const __half2*)&u.y);
                acc.x += pj * f01.x; acc.y += pj * f01.y;
                acc.z += pj * f23.x; acc.w += pj * f23.y;
            }
        }
        idxA = nidxA; asA = nasA; vA = nvA;
        idxB = nidxB; asB = nasB; vB = nvB;
    }

    float li = 1.f / (l + 1e-16f);
    float4 b4 = ((const float4*)bias)[tl];
    float4 o;
    o.x = fmaxf(acc.x * li + b4.x, 0.f);
    o.y = fmaxf(acc.y * li + b4.y, 0.f);
    o.z = fmaxf(acc.z * li + b4.z, 0.f);
    o.w = fmaxf(acc.w * li + b4.w, 0.f);
    ((float4*)out)[(size_t)node * GS + tl] = o;
}

// fp32 fused variant (layer 2, 1 head, GS=8), 16-edge chunks

template <int H_>
__global__ __launch_bounds__(256)
void gat_fused_kernel(const float* __restrict__ Hm,
                      const float* __restrict__ as_,
                      const float* __restrict__ ad_,
                      const int* __restrict__ rowptr,
                      const int* __restrict__ csr,
                      const float* __restrict__ bias,
                      float* __restrict__ out, int n) {
    constexpr int GS  = H_ * 8;
    constexpr int NPB = 256 / GS;
    int t = threadIdx.x;
    int node = blockIdx.x * NPB + t / GS;
    if (node >= n) return;
    int tl = t % GS;
    int h  = tl >> 3;
    int k8 = tl & 7;
    const float4* H4 = (const float4*)Hm;
    int e0 = rowptr[node], e1 = rowptr[node + 1];
    float ad_d = ad_[(size_t)node * H_ + h];

    int  ceA  = e0 + k8;
    int  ceB  = e0 + 8 + k8;
    bool vA   = ceA < e1;
    bool vB   = ceB < e1;
    int  idxA = vA ? csr[ceA] : 0;
    int  idxB = vB ? csr[ceB] : 0;
    float asA = vA ? as_[(size_t)idxA * H_ + h] : 0.f;
    float asB = vB ? as_[(size_t)idxB * H_ + h] : 0.f;

    float m = -INFINITY, l = 0.f;
    float4 acc = make_float4(0.f, 0.f, 0.f, 0.f);

    for (int eb = e0; eb < e1; eb += 16) {
        int  neA   = eb + 16 + k8;
        int  neB   = eb + 24 + k8;
        bool nvA   = neA < e1;
        bool nvB   = neB < e1;
        int  nidxA = nvA ? csr[neA] : 0;
        int  nidxB = nvB ? csr[neB] : 0;
        float nasA = nvA ? as_[(size_t)nidxA * H_ + h] : 0.f;
        float nasB = nvB ? as_[(size_t)nidxB * H_ + h] : 0.f;

        float elA = asA + ad_d;
        elA = (elA > 0.f) ? elA : NEG_SLOPE * elA;
        elA = vA ? elA : -INFINITY;
        float elB = asB + ad_d;
        elB = (elB > 0.f) ? elB : NEG_SLOPE * elB;
        elB = vB ? elB : -INFINITY;

        float cm = fmaxf(elA, elB);
        cm = fmaxf(cm, __shfl_xor(cm, 1, 8));
        cm = fmaxf(cm, __shfl_xor(cm, 2, 8));
        cm = fmaxf(cm, __shfl_xor(cm, 4, 8));
        float m_new = fmaxf(m, cm);
        float scale = __expf(m - m_new);
        float pA = vA ? __expf(elA - m_new) : 0.f;
        float pB = vB ? __expf(elB - m_new) : 0.f;

        float ps = pA + pB;
        ps += __shfl_xor(ps, 1, 8);
        ps += __shfl_xor(ps, 2, 8);
        ps += __shfl_xor(ps, 4, 8);
        l = l * scale + ps;
        acc.x *= scale; acc.y *= scale; acc.z *= scale; acc.w *= scale;
        m = m_new;

        int cnt = e1 - eb; if (cnt > 16) cnt = 16;
        if (cnt == 16) {
#pragma unroll
            for (int j = 0; j < 8; j++) {
                int   srcA = __shfl(idxA, j, 8);
                int   srcB = __shfl(idxB, j, 8);
                float pjA  = __shfl(pA, j, 8);
                float pjB  = __shfl(pB, j, 8);
                float4 hA = H4[(size_t)srcA * GS + tl];
                float4 hB = H4[(size_t)srcB * GS + tl];
                acc.x += pjA * hA.x; acc.y += pjA * hA.y;
                acc.z += pjA * hA.z; acc.w += pjA * hA.w;
                acc.x += pjB * hB.x; acc.y += pjB * hB.y;
                acc.z += pjB * hB.z; acc.w += pjB * hB.w;
            }
        } else {
            int cA = (cnt < 8) ? cnt : 8;
            for (int j = 0; j < cA; j++) {
                int   src = __shfl(idxA, j, 8);
                float pj  = __shfl(pA, j, 8);
                float4 hv = H4[(size_t)src * GS + tl];
                acc.x += pj * hv.x; acc.y += pj * hv.y;
                acc.z += pj * hv.z; acc.w += pj * hv.w;
            }
            int cB = cnt - 8;
            for (int j = 0; j < cB; j++) {
                int   src = __shfl(idxB, j, 8);
                float pj  = __shfl(pB, j, 8);
                float4 hv = H4[(size_t)src * GS + tl];
                acc.x += pj * hv.x; acc.y += pj * hv.y;
                acc.z += pj * hv.z; acc.w += pj * hv.w;
            }
        }
        idxA = nidxA; asA = nasA; vA = nvA;
        idxB = nidxB; asB = nasB; vB = nvB;
    }

    float li = 1.f / (l + 1e-16f);
    float4 b4 = ((const float4*)bias)[tl];
    float4 o;
    o.x = fmaxf(acc.x * li + b4.x, 0.f);
    o.y = fmaxf(acc.y * li + b4.y, 0.f);
    o.z = fmaxf(acc.z * li + b4.z, 0.f);
    o.w = fmaxf(acc.w * li + b4.w, 0.f);
    ((float4*)out)[(size_t)node * GS + tl] = o;
}

// ---------------- final linear: out[n,40] = X[n,32] @ lw[32,40] + lb -------

__global__ void final_linear_kernel(const float* __restrict__ X,
                                    const float* __restrict__ lw,
                                    const float* __restrict__ lb,
                                    float* __restrict__ out, int n) {
    int i = blockIdx.x * blockDim.x + threadIdx.x;
    if (i >= n * 40) return;
    int node = i / 40, cls = i % 40;
    const float* xp = X + (size_t)node * 32;
    float acc = lb[cls];
#pragma unroll
    for (int k = 0; k < 32; k++) acc += xp[k] * lw[k * 40 + cls];
    out[i] = acc;
}

// ---------------- launch ----------------

extern "C" void kernel_launch(void* const* d_in, const int* in_sizes, int n_in,
                              void* d_out, int out_size, void* d_ws, size_t ws_size,
                              hipStream_t stream) {
    const float* x   = (const float*)d_in[0];
    const int*   ei  = (const int*)d_in[1];
    const float* W0  = (const float*)d_in[2];
    const float* as0 = (const float*)d_in[3];
    const float* ad0 = (const float*)d_in[4];
    const float* b0  = (const float*)d_in[5];
    const float* W1  = (const float*)d_in[6];
    const float* as1 = (const float*)d_in[7];
    const float* ad1 = (const float*)d_in[8];
    const float* b1  = (const float*)d_in[9];
    const float* W2  = (const float*)d_in[10];
    const float* as2 = (const float*)d_in[11];
    const float* ad2 = (const float*)d_in[12];
    const float* b2  = (const float*)d_in[13];
    const float* lw  = (const float*)d_in[14];
    const float* lb  = (const float*)d_in[15];
    float* out = (float*)d_out;

    const int n    = in_sizes[0] / 128;   // 100000 (= 32 * 3125)
    const int eraw = in_sizes[1] / 2;     // 1600000
    const int etot = eraw + n;
    const int nb   = (n + 1023) / 1024;

    char* wsp = (char*)d_ws;
    size_t off = 0;
    auto alloc = [&](size_t bytes) -> void* {
        void* p = wsp + off;
        off += (bytes + 255) & ~(size_t)255;
        return p;
    };
    float*  hbuf   = (float*)alloc((size_t)n * 128 * 4);   // fp32 h (layer 2)
    float*  bufA   = (float*)alloc((size_t)n * 128 * 4);   // layer outputs
    __half* h16    = (__half*)alloc((size_t)n * 128 * 2);  // fp16 h (layers 0/1)
    float*  asb    = (float*)alloc((size_t)n * 4 * 4);
    float*  adb    = (float*)alloc((size_t)n * 4 * 4);
    int*    deg    = (int*)alloc((size_t)n * 4);
    int*    rank   = (int*)alloc((size_t)etot * 4);
    int*    rowptr = (int*)alloc((size_t)(n + 1) * 4);
    int*    csr    = (int*)alloc((size_t)etot * 4);
    int*    bsum   = (int*)alloc((size_t)nb * 4);
    int*    boffs  = (int*)alloc((size_t)nb * 4);

    // --- CSR build (single atomic pass) ---
    zero1_kernel<<<(n + 255) / 256, 256, 0, stream>>>(deg, n);
    count_rank_kernel<<<(etot + 255) / 256, 256, 0, stream>>>(ei, eraw, n, deg, rank);
    scan_local_kernel<<<nb, 1024, 0, stream>>>(deg, rowptr, bsum, n);
    scan_sums_kernel<<<1, 128, 0, stream>>>(bsum, boffs, nb);
    scan_add_kernel<<<(n + 255) / 256, 256, 0, stream>>>(rowptr, boffs, n, etot);
    scatter2_kernel<<<(etot + 255) / 256, 256, 0, stream>>>(ei, rank, eraw, n, rowptr, csr);

    // --- layer 0: 128 -> 4x32, concat (fp16 H) ---
    gemm_rt_f16_kernel<<<n / 32, 256, 0, stream>>>(x, W0, h16, n);
    attn_coef_f16_kernel<<<(n * 4 + 255) / 256, 256, 0, stream>>>(h16, as0, ad0, asb, adb, n);
    gat_fused_f16_kernel<<<(n + 7) / 8, 256, 0, stream>>>(h16, asb, adb, rowptr, csr, b0, bufA, n);

    // --- layer 1: 128 -> 4x32, concat (fp16 H) ---
    gemm_rt_f16_kernel<<<n / 32, 256, 0, stream>>>(bufA, W1, h16, n);
    attn_coef_f16_kernel<<<(n * 4 + 255) / 256, 256, 0, stream>>>(h16, as1, ad1, asb, adb, n);
    gat_fused_f16_kernel<<<(n + 7) / 8, 256, 0, stream>>>(h16, asb, adb, rowptr, csr, b1, bufA, n);

    // --- layer 2: 128 -> 1x32 (fp32 throughout) ---
    gemm_kernel<32, 8><<<(n + 7) / 8, 128, 0, stream>>>(bufA, W2, hbuf, n);
    attn_coef_kernel<1, 32><<<(n + 255) / 256, 256, 0, stream>>>(hbuf, as2, ad2, asb, adb, n);
    gat_fused_kernel<1><<<(n + 31) / 32, 256, 0, stream>>>(hbuf, asb, adb, rowptr, csr, b2, bufA, n);

    // --- final linear 32 -> 40 ---
    final_linear_kernel<<<(n * 40 + 255) / 256, 256, 0, stream>>>(bufA, lw, lb, out, n);
}

// Round 3
// 629.302 us; speedup vs baseline: 1.1191x; 1.1191x over previous
//
#include <hip/hip_runtime.h>
#include <hip/hip_bf16.h>
#include <hip/hip_fp16.h>
#include <math.h>

// ---------------------------------------------------------------------------
// GAT (3 layers, heads=4/4/1, hid=32) + final linear, fp32 compute.
// R14: revert to 8-edge chunks (R12/13's 16-edge chunk regressed 95.6->112us:
//      it moved ~50% of edges into the serial non-unrolled tail path).
//      Change vs R11: BRANCHLESS inner loop - always run the unrolled
//      8-gather loop; invalid lanes have p=0 and idx=0 (safe hot row), so
//      their contribution is exactly 0. Removes the cnt branch + serial tail
//      (~26% of edges at ~2x cost). Applied to f16 and fp32 fused kernels.
// ---------------------------------------------------------------------------

#define NEG_SLOPE 0.2f

// ---------------- CSR build ----------------

__global__ void zero1_kernel(int* __restrict__ a, int n) {
    int i = blockIdx.x * blockDim.x + threadIdx.x;
    if (i < n) a[i] = 0;
}

__global__ void count_rank_kernel(const int* __restrict__ ei, int eraw, int n,
                                  int* __restrict__ deg, int* __restrict__ rank) {
    int i = blockIdx.x * blockDim.x + threadIdx.x;
    int etot = eraw + n;
    if (i >= etot) return;
    int dst = (i < eraw) ? ei[eraw + i] : (i - eraw);
    rank[i] = atomicAdd(&deg[dst], 1);
}

__global__ __launch_bounds__(1024)
void scan_local_kernel(const int* __restrict__ deg, int* __restrict__ rowptr,
                       int* __restrict__ bsum, int n) {
    __shared__ int buf[1024];
    int tid = threadIdx.x;
    int i = blockIdx.x * 1024 + tid;
    int v = (i < n) ? deg[i] : 0;
    buf[tid] = v;
    __syncthreads();
    for (int off = 1; off < 1024; off <<= 1) {
        int t = (tid >= off) ? buf[tid - off] : 0;
        __syncthreads();
        buf[tid] += t;
        __syncthreads();
    }
    if (i < n) rowptr[i] = buf[tid] - v;
    if (tid == 1023) bsum[blockIdx.x] = buf[1023];
}

__global__ __launch_bounds__(128)
void scan_sums_kernel(const int* __restrict__ bsum, int* __restrict__ boffs, int nb) {
    __shared__ int buf[128];
    int tid = threadIdx.x;
    int v = (tid < nb) ? bsum[tid] : 0;
    buf[tid] = v;
    __syncthreads();
    for (int off = 1; off < 128; off <<= 1) {
        int t = (tid >= off) ? buf[tid - off] : 0;
        __syncthreads();
        buf[tid] += t;
        __syncthreads();
    }
    if (tid < nb) boffs[tid] = buf[tid] - v;
}

__global__ void scan_add_kernel(int* __restrict__ rowptr, const int* __restrict__ boffs,
                                int n, int etot) {
    int i = blockIdx.x * blockDim.x + threadIdx.x;
    if (i < n) rowptr[i] += boffs[i >> 10];
    if (i == 0) rowptr[n] = etot;
}

__global__ void scatter2_kernel(const int* __restrict__ ei, const int* __restrict__ rank,
                                int eraw, int n, const int* __restrict__ rowptr,
                                int* __restrict__ csr_src) {
    int i = blockIdx.x * blockDim.x + threadIdx.x;
    int etot = eraw + n;
    if (i >= etot) return;
    int src, dst;
    if (i < eraw) { src = ei[i]; dst = ei[eraw + i]; }
    else          { src = i - eraw; dst = src; }
    csr_src[rowptr[dst] + rank[i]] = src;
}

// ---------------- register-tiled GEMM, fp16 output -------------------------
// H16[n,128] = X[n,128] @ W[128,128], stored as __half. n % 32 == 0.

struct h4pack { __half2 a, b; };   // 4 halves = 8 B

__global__ __launch_bounds__(256)
void gemm_rt_f16_kernel(const float* __restrict__ X, const float* __restrict__ W,
                        __half* __restrict__ H, int n) {
    __shared__ float xsT[128][36];
    int t = threadIdx.x;
    int base = blockIdx.x * 32;
    {
        int r  = t >> 3;
        int k0 = (t & 7) << 4;
        const float4* xp = (const float4*)(X + (size_t)(base + r) * 128 + k0);
        float4 a = xp[0], b = xp[1], c = xp[2], d = xp[3];
        xsT[k0 +  0][r] = a.x; xsT[k0 +  1][r] = a.y; xsT[k0 +  2][r] = a.z; xsT[k0 +  3][r] = a.w;
        xsT[k0 +  4][r] = b.x; xsT[k0 +  5][r] = b.y; xsT[k0 +  6][r] = b.z; xsT[k0 +  7][r] = b.w;
        xsT[k0 +  8][r] = c.x; xsT[k0 +  9][r] = c.y; xsT[k0 + 10][r] = c.z; xsT[k0 + 11][r] = c.w;
        xsT[k0 + 12][r] = d.x; xsT[k0 + 13][r] = d.y; xsT[k0 + 14][r] = d.z; xsT[k0 + 15][r] = d.w;
    }
    __syncthreads();

    int tx = t & 31;
    int ty = t >> 5;
    float4 acc0 = make_float4(0.f, 0.f, 0.f, 0.f);
    float4 acc1 = acc0, acc2 = acc0, acc3 = acc0;
    const float4* W4 = (const float4*)W;

#pragma unroll 4
    for (int k = 0; k < 128; k++) {
        float4 w  = W4[k * 32 + tx];
        float4 xv = *(const float4*)(&xsT[k][ty << 2]);
        acc0.x += xv.x * w.x; acc0.y += xv.x * w.y; acc0.z += xv.x * w.z; acc0.w += xv.x * w.w;
        acc1.x += xv.y * w.x; acc1.y += xv.y * w.y; acc1.z += xv.y * w.z; acc1.w += xv.y * w.w;
        acc2.x += xv.z * w.x; acc2.y += xv.z * w.y; acc2.z += xv.z * w.z; acc2.w += xv.z * w.w;
        acc3.x += xv.w * w.x; acc3.y += xv.w * w.y; acc3.z += xv.w * w.z; acc3.w += xv.w * w.w;
    }

    size_t row0 = (size_t)(base + (ty << 2));
    h4pack* hp = (h4pack*)(H + row0 * 128) + tx;      // row stride = 32 h4pack
    h4pack p;
    p.a = __floats2half2_rn(acc0.x, acc0.y); p.b = __floats2half2_rn(acc0.z, acc0.w);
    hp[0]  = p;
    p.a = __floats2half2_rn(acc1.x, acc1.y); p.b = __floats2half2_rn(acc1.z, acc1.w);
    hp[32] = p;
    p.a = __floats2half2_rn(acc2.x, acc2.y); p.b = __floats2half2_rn(acc2.z, acc2.w);
    hp[64] = p;
    p.a = __floats2half2_rn(acc3.x, acc3.y); p.b = __floats2half2_rn(acc3.z, acc3.w);
    hp[96] = p;
}

// ---------------- fallback GEMM (layer 2, OUTC=32, fp32) -------------------

template <int OUTC, int ROWS>
__global__ __launch_bounds__(128)
void gemm_kernel(const float* __restrict__ X, const float* __restrict__ W,
                 float* __restrict__ H, int n) {
    constexpr int GROUPS = 128 / OUTC;
    constexpr int RPT = ROWS / GROUPS;
    __shared__ float xs[ROWS][129];
    int base = blockIdx.x * ROWS;
    for (int i = threadIdx.x; i < ROWS * 128; i += 128) {
        int r = i >> 7, c = i & 127;
        int row = base + r;
        xs[r][c] = (row < n) ? X[(size_t)row * 128 + c] : 0.f;
    }
    __syncthreads();
    int col  = threadIdx.x % OUTC;
    int rsub = threadIdx.x / OUTC;
    float acc[RPT];
#pragma unroll
    for (int j = 0; j < RPT; j++) acc[j] = 0.f;
    for (int k = 0; k < 128; k++) {
        float w = W[k * OUTC + col];
#pragma unroll
        for (int j = 0; j < RPT; j++)
            acc[j] += xs[rsub + j * GROUPS][k] * w;
    }
#pragma unroll
    for (int j = 0; j < RPT; j++) {
        int row = base + rsub + j * GROUPS;
        if (row < n) H[(size_t)row * OUTC + col] = acc[j];
    }
}

// ---------------- attention coefficients (fp16 H) --------------------------

__global__ void attn_coef_f16_kernel(const __half* __restrict__ H,
                                     const float* __restrict__ a_s,
                                     const float* __restrict__ a_d,
                                     float* __restrict__ as_out,
                                     float* __restrict__ ad_out, int n) {
    int i = blockIdx.x * blockDim.x + threadIdx.x;
    if (i >= n * 4) return;
    int node = i >> 2, h = i & 3;
    const __half2* hp = (const __half2*)(H + (size_t)node * 128 + h * 32);
    float s = 0.f, d = 0.f;
#pragma unroll
    for (int c2 = 0; c2 < 16; c2++) {
        float2 v = __half22float2(hp[c2]);
        s += v.x * a_s[h * 32 + c2 * 2] + v.y * a_s[h * 32 + c2 * 2 + 1];
        d += v.x * a_d[h * 32 + c2 * 2] + v.y * a_d[h * 32 + c2 * 2 + 1];
    }
    as_out[i] = s;
    ad_out[i] = d;
}

// fp32 variant (layer 2)
template <int HEADS_, int C_>
__global__ void attn_coef_kernel(const float* __restrict__ H,
                                 const float* __restrict__ a_s,
                                 const float* __restrict__ a_d,
                                 float* __restrict__ as_out,
                                 float* __restrict__ ad_out, int n) {
    int i = blockIdx.x * blockDim.x + threadIdx.x;
    if (i >= n * HEADS_) return;
    int node = i / HEADS_, h = i % HEADS_;
    const float* hp = H + ((size_t)node * HEADS_ + h) * C_;
    float s = 0.f, d = 0.f;
#pragma unroll
    for (int c = 0; c < C_; c++) {
        float v = hp[c];
        s += v * a_s[h * C_ + c];
        d += v * a_d[h * C_ + c];
    }
    as_out[i] = s;
    ad_out[i] = d;
}

// ---------------- fused online-softmax aggregation, fp16 gathers -----------
// 4 heads, GS=32 lanes/node; lane tl covers channels 4tl..4tl+3 (8 B fp16).
// R14: branchless - the 8-gather loop is ALWAYS fully unrolled; lanes past
// the row end carry p=0 and idx=0 so their contribution is exactly zero.

__global__ __launch_bounds__(256)
void gat_fused_f16_kernel(const __half* __restrict__ Hm,
                          const float* __restrict__ as_,
                          const float* __restrict__ ad_,
                          const int* __restrict__ rowptr,
                          const int* __restrict__ csr,
                          const float* __restrict__ bias,
                          float* __restrict__ out, int n) {
    constexpr int GS = 32;
    int t = threadIdx.x;
    int node = blockIdx.x * 8 + (t >> 5);
    if (node >= n) return;
    int tl = t & 31;
    int h  = tl >> 3;
    int k8 = tl & 7;
    const uint2* H8 = (const uint2*)Hm;     // 8 B = 4 halves per lane
    int e0 = rowptr[node], e1 = rowptr[node + 1];
    float ad_d = ad_[(size_t)node * 4 + h];

    int  ce  = e0 + k8;
    bool vA  = ce < e1;
    int  idxA = vA ? csr[ce] : 0;
    float asA = vA ? as_[(size_t)idxA * 4 + h] : 0.f;

    float m = -INFINITY, l = 0.f;
    float4 acc = make_float4(0.f, 0.f, 0.f, 0.f);

    for (int eb = e0; eb < e1; eb += 8) {
        int  ne  = eb + 8 + k8;
        bool vB  = ne < e1;
        int  idxB = vB ? csr[ne] : 0;
        float asB = vB ? as_[(size_t)idxB * 4 + h] : 0.f;

        float el = asA + ad_d;
        el = (el > 0.f) ? el : NEG_SLOPE * el;
        el = vA ? el : -INFINITY;

        float cm = el;
        cm = fmaxf(cm, __shfl_xor(cm, 1, 8));
        cm = fmaxf(cm, __shfl_xor(cm, 2, 8));
        cm = fmaxf(cm, __shfl_xor(cm, 4, 8));
        float m_new = fmaxf(m, cm);
        float scale = __expf(m - m_new);
        float p = vA ? __expf(el - m_new) : 0.f;

        float ps = p;
        ps += __shfl_xor(ps, 1, 8);
        ps += __shfl_xor(ps, 2, 8);
        ps += __shfl_xor(ps, 4, 8);
        l = l * scale + ps;
        acc.x *= scale; acc.y *= scale; acc.z *= scale; acc.w *= scale;
        m = m_new;

        // branchless: always 8 unrolled gathers; invalid lanes have p=0,idx=0
#pragma unroll
        for (int j = 0; j < 8; j++) {
            int   src = __shfl(idxA, j, 8);
            float pj  = __shfl(p, j, 8);
            uint2 u = H8[(size_t)src * GS + tl];
            float2 f01 = __half22float2(*(const __half2*)&u.x);
            float2 f23 = __half22float2(*(const __half2*)&u.y);
            acc.x += pj * f01.x; acc.y += pj * f01.y;
            acc.z += pj * f23.x; acc.w += pj * f23.y;
        }
        idxA = idxB; asA = asB; vA = vB;
    }

    float li = 1.f / (l + 1e-16f);
    float4 b4 = ((const float4*)bias)[tl];
    float4 o;
    o.x = fmaxf(acc.x * li + b4.x, 0.f);
    o.y = fmaxf(acc.y * li + b4.y, 0.f);
    o.z = fmaxf(acc.z * li + b4.z, 0.f);
    o.w = fmaxf(acc.w * li + b4.w, 0.f);
    ((float4*)out)[(size_t)node * GS + tl] = o;
}

// fp32 fused variant (layer 2, 1 head, GS=8), branchless

template <int H_>
__global__ __launch_bounds__(256)
void gat_fused_kernel(const float* __restrict__ Hm,
                      const float* __restrict__ as_,
                      const float* __restrict__ ad_,
                      const int* __restrict__ rowptr,
                      const int* __restrict__ csr,
                      const float* __restrict__ bias,
                      float* __restrict__ out, int n) {
    constexpr int GS  = H_ * 8;
    constexpr int NPB = 256 / GS;
    int t = threadIdx.x;
    int node = blockIdx.x * NPB + t / GS;
    if (node >= n) return;
    int tl = t % GS;
    int h  = tl >> 3;
    int k8 = tl & 7;
    const float4* H4 = (const float4*)Hm;
    int e0 = rowptr[node], e1 = rowptr[node + 1];
    float ad_d = ad_[(size_t)node * H_ + h];

    int  ce  = e0 + k8;
    bool vA  = ce < e1;
    int  idxA = vA ? csr[ce] : 0;
    float asA = vA ? as_[(size_t)idxA * H_ + h] : 0.f;

    float m = -INFINITY, l = 0.f;
    float4 acc = make_float4(0.f, 0.f, 0.f, 0.f);

    for (int eb = e0; eb < e1; eb += 8) {
        int  ne  = eb + 8 + k8;
        bool vB  = ne < e1;
        int  idxB = vB ? csr[ne] : 0;
        float asB = vB ? as_[(size_t)idxB * H_ + h] : 0.f;

        float el = asA + ad_d;
        el = (el > 0.f) ? el : NEG_SLOPE * el;
        el = vA ? el : -INFINITY;

        float cm = el;
        cm = fmaxf(cm, __shfl_xor(cm, 1, 8));
        cm = fmaxf(cm, __shfl_xor(cm, 2, 8));
        cm = fmaxf(cm, __shfl_xor(cm, 4, 8));
        float m_new = fmaxf(m, cm);
        float scale = __expf(m - m_new);
        float p = vA ? __expf(el - m_new) : 0.f;

        float ps = p;
        ps += __shfl_xor(ps, 1, 8);
        ps += __shfl_xor(ps, 2, 8);
        ps += __shfl_xor(ps, 4, 8);
        l = l * scale + ps;
        acc.x *= scale; acc.y *= scale; acc.z *= scale; acc.w *= scale;
        m = m_new;

#pragma unroll
        for (int j = 0; j < 8; j++) {
            int   src = __shfl(idxA, j, 8);
            float pj  = __shfl(p, j, 8);
            float4 hv = H4[(size_t)src * GS + tl];
            acc.x += pj * hv.x; acc.y += pj * hv.y;
            acc.z += pj * hv.z; acc.w += pj * hv.w;
        }
        idxA = idxB; asA = asB; vA = vB;
    }

    float li = 1.f / (l + 1e-16f);
    float4 b4 = ((const float4*)bias)[tl];
    float4 o;
    o.x = fmaxf(acc.x * li + b4.x, 0.f);
    o.y = fmaxf(acc.y * li + b4.y, 0.f);
    o.z = fmaxf(acc.z * li + b4.z, 0.f);
    o.w = fmaxf(acc.w * li + b4.w, 0.f);
    ((float4*)out)[(size_t)node * GS + tl] = o;
}

// ---------------- final linear: out[n,40] = X[n,32] @ lw[32,40] + lb -------

__global__ void final_linear_kernel(const float* __restrict__ X,
                                    const float* __restrict__ lw,
                                    const float* __restrict__ lb,
                                    float* __restrict__ out, int n) {
    int i = blockIdx.x * blockDim.x + threadIdx.x;
    if (i >= n * 40) return;
    int node = i / 40, cls = i % 40;
    const float* xp = X + (size_t)node * 32;
    float acc = lb[cls];
#pragma unroll
    for (int k = 0; k < 32; k++) acc += xp[k] * lw[k * 40 + cls];
    out[i] = acc;
}

// ---------------- launch ----------------

extern "C" void kernel_launch(void* const* d_in, const int* in_sizes, int n_in,
                              void* d_out, int out_size, void* d_ws, size_t ws_size,
                              hipStream_t stream) {
    const float* x   = (const float*)d_in[0];
    const int*   ei  = (const int*)d_in[1];
    const float* W0  = (const float*)d_in[2];
    const float* as0 = (const float*)d_in[3];
    const float* ad0 = (const float*)d_in[4];
    const float* b0  = (const float*)d_in[5];
    const float* W1  = (const float*)d_in[6];
    const float* as1 = (const float*)d_in[7];
    const float* ad1 = (const float*)d_in[8];
    const float* b1  = (const float*)d_in[9];
    const float* W2  = (const float*)d_in[10];
    const float* as2 = (const float*)d_in[11];
    const float* ad2 = (const float*)d_in[12];
    const float* b2  = (const float*)d_in[13];
    const float* lw  = (const float*)d_in[14];
    const float* lb  = (const float*)d_in[15];
    float* out = (float*)d_out;

    const int n    = in_sizes[0] / 128;   // 100000 (= 32 * 3125)
    const int eraw = in_sizes[1] / 2;     // 1600000
    const int etot = eraw + n;
    const int nb   = (n + 1023) / 1024;

    char* wsp = (char*)d_ws;
    size_t off = 0;
    auto alloc = [&](size_t bytes) -> void* {
        void* p = wsp + off;
        off += (bytes + 255) & ~(size_t)255;
        return p;
    };
    float*  hbuf   = (float*)alloc((size_t)n * 128 * 4);   // fp32 h (layer 2)
    float*  bufA   = (float*)alloc((size_t)n * 128 * 4);   // layer outputs
    __half* h16    = (__half*)alloc((size_t)n * 128 * 2);  // fp16 h (layers 0/1)
    float*  asb    = (float*)alloc((size_t)n * 4 * 4);
    float*  adb    = (float*)alloc((size_t)n * 4 * 4);
    int*    deg    = (int*)alloc((size_t)n * 4);
    int*    rank   = (int*)alloc((size_t)etot * 4);
    int*    rowptr = (int*)alloc((size_t)(n + 1) * 4);
    int*    csr    = (int*)alloc((size_t)etot * 4);
    int*    bsum   = (int*)alloc((size_t)nb * 4);
    int*    boffs  = (int*)alloc((size_t)nb * 4);

    // --- CSR build (single atomic pass) ---
    zero1_kernel<<<(n + 255) / 256, 256, 0, stream>>>(deg, n);
    count_rank_kernel<<<(etot + 255) / 256, 256, 0, stream>>>(ei, eraw, n, deg, rank);
    scan_local_kernel<<<nb, 1024, 0, stream>>>(deg, rowptr, bsum, n);
    scan_sums_kernel<<<1, 128, 0, stream>>>(bsum, boffs, nb);
    scan_add_kernel<<<(n + 255) / 256, 256, 0, stream>>>(rowptr, boffs, n, etot);
    scatter2_kernel<<<(etot + 255) / 256, 256, 0, stream>>>(ei, rank, eraw, n, rowptr, csr);

    // --- layer 0: 128 -> 4x32, concat (fp16 H) ---
    gemm_rt_f16_kernel<<<n / 32, 256, 0, stream>>>(x, W0, h16, n);
    attn_coef_f16_kernel<<<(n * 4 + 255) / 256, 256, 0, stream>>>(h16, as0, ad0, asb, adb, n);
    gat_fused_f16_kernel<<<(n + 7) / 8, 256, 0, stream>>>(h16, asb, adb, rowptr, csr, b0, bufA, n);

    // --- layer 1: 128 -> 4x32, concat (fp16 H) ---
    gemm_rt_f16_kernel<<<n / 32, 256, 0, stream>>>(bufA, W1, h16, n);
    attn_coef_f16_kernel<<<(n * 4 + 255) / 256, 256, 0, stream>>>(h16, as1, ad1, asb, adb, n);
    gat_fused_f16_kernel<<<(n + 7) / 8, 256, 0, stream>>>(h16, asb, adb, rowptr, csr, b1, bufA, n);

    // --- layer 2: 128 -> 1x32 (fp32 throughout) ---
    gemm_kernel<32, 8><<<(n + 7) / 8, 128, 0, stream>>>(bufA, W2, hbuf, n);
    attn_coef_kernel<1, 32><<<(n + 255) / 256, 256, 0, stream>>>(hbuf, as2, ad2, asb, adb, n);
    gat_fused_kernel<1><<<(n + 31) / 32, 256, 0, stream>>>(hbuf, asb, adb, rowptr, csr, b2, bufA, n);

    // --- final linear 32 -> 40 ---
    final_linear_kernel<<<(n * 40 + 255) / 256, 256, 0, stream>>>(bufA, lw, lb, out, n);
}

// Round 4
// 613.542 us; speedup vs baseline: 1.1478x; 1.0257x over previous
//
#include <hip/hip_runtime.h>
#include <hip/hip_bf16.h>
#include <hip/hip_fp16.h>
#include <math.h>

// ---------------------------------------------------------------------------
// GAT (3 layers, heads=4/4/1, hid=32) + final linear, fp32 compute.
// R15: fused kernels remain latency-bound after R14 (75.6us, VALU 42%, HBM 49%,
//      occ 62% - nothing saturated; R14's +MLP change gave -21%). Restructure
//      chunk body: issue all 8 H-row gathers FIRST (addresses depend only on
//      idxA, known at chunk entry), then next-chunk idx/as prefetch, then the
//      serial softmax chain (hidden under the in-flight gathers), then consume.
//      u[8] statically indexed after full unroll -> registers, +16 VGPR (f16)
//      / +32 VGPR (fp32 layer-2 variant).
// ---------------------------------------------------------------------------

#define NEG_SLOPE 0.2f

// ---------------- CSR build ----------------

__global__ void zero1_kernel(int* __restrict__ a, int n) {
    int i = blockIdx.x * blockDim.x + threadIdx.x;
    if (i < n) a[i] = 0;
}

__global__ void count_rank_kernel(const int* __restrict__ ei, int eraw, int n,
                                  int* __restrict__ deg, int* __restrict__ rank) {
    int i = blockIdx.x * blockDim.x + threadIdx.x;
    int etot = eraw + n;
    if (i >= etot) return;
    int dst = (i < eraw) ? ei[eraw + i] : (i - eraw);
    rank[i] = atomicAdd(&deg[dst], 1);
}

__global__ __launch_bounds__(1024)
void scan_local_kernel(const int* __restrict__ deg, int* __restrict__ rowptr,
                       int* __restrict__ bsum, int n) {
    __shared__ int buf[1024];
    int tid = threadIdx.x;
    int i = blockIdx.x * 1024 + tid;
    int v = (i < n) ? deg[i] : 0;
    buf[tid] = v;
    __syncthreads();
    for (int off = 1; off < 1024; off <<= 1) {
        int t = (tid >= off) ? buf[tid - off] : 0;
        __syncthreads();
        buf[tid] += t;
        __syncthreads();
    }
    if (i < n) rowptr[i] = buf[tid] - v;
    if (tid == 1023) bsum[blockIdx.x] = buf[1023];
}

__global__ __launch_bounds__(128)
void scan_sums_kernel(const int* __restrict__ bsum, int* __restrict__ boffs, int nb) {
    __shared__ int buf[128];
    int tid = threadIdx.x;
    int v = (tid < nb) ? bsum[tid] : 0;
    buf[tid] = v;
    __syncthreads();
    for (int off = 1; off < 128; off <<= 1) {
        int t = (tid >= off) ? buf[tid - off] : 0;
        __syncthreads();
        buf[tid] += t;
        __syncthreads();
    }
    if (tid < nb) boffs[tid] = buf[tid] - v;
}

__global__ void scan_add_kernel(int* __restrict__ rowptr, const int* __restrict__ boffs,
                                int n, int etot) {
    int i = blockIdx.x * blockDim.x + threadIdx.x;
    if (i < n) rowptr[i] += boffs[i >> 10];
    if (i == 0) rowptr[n] = etot;
}

__global__ void scatter2_kernel(const int* __restrict__ ei, const int* __restrict__ rank,
                                int eraw, int n, const int* __restrict__ rowptr,
                                int* __restrict__ csr_src) {
    int i = blockIdx.x * blockDim.x + threadIdx.x;
    int etot = eraw + n;
    if (i >= etot) return;
    int src, dst;
    if (i < eraw) { src = ei[i]; dst = ei[eraw + i]; }
    else          { src = i - eraw; dst = src; }
    csr_src[rowptr[dst] + rank[i]] = src;
}

// ---------------- register-tiled GEMM, fp16 output -------------------------
// H16[n,128] = X[n,128] @ W[128,128], stored as __half. n % 32 == 0.

struct h4pack { __half2 a, b; };   // 4 halves = 8 B

__global__ __launch_bounds__(256)
void gemm_rt_f16_kernel(const float* __restrict__ X, const float* __restrict__ W,
                        __half* __restrict__ H, int n) {
    __shared__ float xsT[128][36];
    int t = threadIdx.x;
    int base = blockIdx.x * 32;
    {
        int r  = t >> 3;
        int k0 = (t & 7) << 4;
        const float4* xp = (const float4*)(X + (size_t)(base + r) * 128 + k0);
        float4 a = xp[0], b = xp[1], c = xp[2], d = xp[3];
        xsT[k0 +  0][r] = a.x; xsT[k0 +  1][r] = a.y; xsT[k0 +  2][r] = a.z; xsT[k0 +  3][r] = a.w;
        xsT[k0 +  4][r] = b.x; xsT[k0 +  5][r] = b.y; xsT[k0 +  6][r] = b.z; xsT[k0 +  7][r] = b.w;
        xsT[k0 +  8][r] = c.x; xsT[k0 +  9][r] = c.y; xsT[k0 + 10][r] = c.z; xsT[k0 + 11][r] = c.w;
        xsT[k0 + 12][r] = d.x; xsT[k0 + 13][r] = d.y; xsT[k0 + 14][r] = d.z; xsT[k0 + 15][r] = d.w;
    }
    __syncthreads();

    int tx = t & 31;
    int ty = t >> 5;
    float4 acc0 = make_float4(0.f, 0.f, 0.f, 0.f);
    float4 acc1 = acc0, acc2 = acc0, acc3 = acc0;
    const float4* W4 = (const float4*)W;

#pragma unroll 4
    for (int k = 0; k < 128; k++) {
        float4 w  = W4[k * 32 + tx];
        float4 xv = *(const float4*)(&xsT[k][ty << 2]);
        acc0.x += xv.x * w.x; acc0.y += xv.x * w.y; acc0.z += xv.x * w.z; acc0.w += xv.x * w.w;
        acc1.x += xv.y * w.x; acc1.y += xv.y * w.y; acc1.z += xv.y * w.z; acc1.w += xv.y * w.w;
        acc2.x += xv.z * w.x; acc2.y += xv.z * w.y; acc2.z += xv.z * w.z; acc2.w += xv.z * w.w;
        acc3.x += xv.w * w.x; acc3.y += xv.w * w.y; acc3.z += xv.w * w.z; acc3.w += xv.w * w.w;
    }

    size_t row0 = (size_t)(base + (ty << 2));
    h4pack* hp = (h4pack*)(H + row0 * 128) + tx;      // row stride = 32 h4pack
    h4pack p;
    p.a = __floats2half2_rn(acc0.x, acc0.y); p.b = __floats2half2_rn(acc0.z, acc0.w);
    hp[0]  = p;
    p.a = __floats2half2_rn(acc1.x, acc1.y); p.b = __floats2half2_rn(acc1.z, acc1.w);
    hp[32] = p;
    p.a = __floats2half2_rn(acc2.x, acc2.y); p.b = __floats2half2_rn(acc2.z, acc2.w);
    hp[64] = p;
    p.a = __floats2half2_rn(acc3.x, acc3.y); p.b = __floats2half2_rn(acc3.z, acc3.w);
    hp[96] = p;
}

// ---------------- fallback GEMM (layer 2, OUTC=32, fp32) -------------------

template <int OUTC, int ROWS>
__global__ __launch_bounds__(128)
void gemm_kernel(const float* __restrict__ X, const float* __restrict__ W,
                 float* __restrict__ H, int n) {
    constexpr int GROUPS = 128 / OUTC;
    constexpr int RPT = ROWS / GROUPS;
    __shared__ float xs[ROWS][129];
    int base = blockIdx.x * ROWS;
    for (int i = threadIdx.x; i < ROWS * 128; i += 128) {
        int r = i >> 7, c = i & 127;
        int row = base + r;
        xs[r][c] = (row < n) ? X[(size_t)row * 128 + c] : 0.f;
    }
    __syncthreads();
    int col  = threadIdx.x % OUTC;
    int rsub = threadIdx.x / OUTC;
    float acc[RPT];
#pragma unroll
    for (int j = 0; j < RPT; j++) acc[j] = 0.f;
    for (int k = 0; k < 128; k++) {
        float w = W[k * OUTC + col];
#pragma unroll
        for (int j = 0; j < RPT; j++)
            acc[j] += xs[rsub + j * GROUPS][k] * w;
    }
#pragma unroll
    for (int j = 0; j < RPT; j++) {
        int row = base + rsub + j * GROUPS;
        if (row < n) H[(size_t)row * OUTC + col] = acc[j];
    }
}

// ---------------- attention coefficients (fp16 H) --------------------------

__global__ void attn_coef_f16_kernel(const __half* __restrict__ H,
                                     const float* __restrict__ a_s,
                                     const float* __restrict__ a_d,
                                     float* __restrict__ as_out,
                                     float* __restrict__ ad_out, int n) {
    int i = blockIdx.x * blockDim.x + threadIdx.x;
    if (i >= n * 4) return;
    int node = i >> 2, h = i & 3;
    const __half2* hp = (const __half2*)(H + (size_t)node * 128 + h * 32);
    float s = 0.f, d = 0.f;
#pragma unroll
    for (int c2 = 0; c2 < 16; c2++) {
        float2 v = __half22float2(hp[c2]);
        s += v.x * a_s[h * 32 + c2 * 2] + v.y * a_s[h * 32 + c2 * 2 + 1];
        d += v.x * a_d[h * 32 + c2 * 2] + v.y * a_d[h * 32 + c2 * 2 + 1];
    }
    as_out[i] = s;
    ad_out[i] = d;
}

// fp32 variant (layer 2)
template <int HEADS_, int C_>
__global__ void attn_coef_kernel(const float* __restrict__ H,
                                 const float* __restrict__ a_s,
                                 const float* __restrict__ a_d,
                                 float* __restrict__ as_out,
                                 float* __restrict__ ad_out, int n) {
    int i = blockIdx.x * blockDim.x + threadIdx.x;
    if (i >= n * HEADS_) return;
    int node = i / HEADS_, h = i % HEADS_;
    const float* hp = H + ((size_t)node * HEADS_ + h) * C_;
    float s = 0.f, d = 0.f;
#pragma unroll
    for (int c = 0; c < C_; c++) {
        float v = hp[c];
        s += v * a_s[h * C_ + c];
        d += v * a_d[h * C_ + c];
    }
    as_out[i] = s;
    ad_out[i] = d;
}

// ---------------- fused online-softmax aggregation, fp16 gathers -----------
// 4 heads, GS=32 lanes/node; lane tl covers channels 4tl..4tl+3 (8 B fp16).
// R15: gathers issued at chunk entry (before softmax chain); branchless
// unrolled consume (invalid lanes carry p=0, idx=0).

__global__ __launch_bounds__(256)
void gat_fused_f16_kernel(const __half* __restrict__ Hm,
                          const float* __restrict__ as_,
                          const float* __restrict__ ad_,
                          const int* __restrict__ rowptr,
                          const int* __restrict__ csr,
                          const float* __restrict__ bias,
                          float* __restrict__ out, int n) {
    constexpr int GS = 32;
    int t = threadIdx.x;
    int node = blockIdx.x * 8 + (t >> 5);
    if (node >= n) return;
    int tl = t & 31;
    int h  = tl >> 3;
    int k8 = tl & 7;
    const uint2* H8 = (const uint2*)Hm;     // 8 B = 4 halves per lane
    int e0 = rowptr[node], e1 = rowptr[node + 1];
    float ad_d = ad_[(size_t)node * 4 + h];

    int  ce  = e0 + k8;
    bool vA  = ce < e1;
    int  idxA = vA ? csr[ce] : 0;
    float asA = vA ? as_[(size_t)idxA * 4 + h] : 0.f;

    float m = -INFINITY, l = 0.f;
    float4 acc = make_float4(0.f, 0.f, 0.f, 0.f);

    for (int eb = e0; eb < e1; eb += 8) {
        // 1. issue this chunk's 8 row gathers (addresses depend only on idxA)
        uint2 u[8];
#pragma unroll
        for (int j = 0; j < 8; j++) {
            int src = __shfl(idxA, j, 8);
            u[j] = H8[(size_t)src * GS + tl];
        }

        // 2. prefetch next chunk's idx + alpha_src
        int  ne  = eb + 8 + k8;
        bool vB  = ne < e1;
        int  idxB = vB ? csr[ne] : 0;
        float asB = vB ? as_[(size_t)idxB * 4 + h] : 0.f;

        // 3. softmax chain (hidden under the in-flight gathers)
        float el = asA + ad_d;
        el = (el > 0.f) ? el : NEG_SLOPE * el;
        el = vA ? el : -INFINITY;

        float cm = el;
        cm = fmaxf(cm, __shfl_xor(cm, 1, 8));
        cm = fmaxf(cm, __shfl_xor(cm, 2, 8));
        cm = fmaxf(cm, __shfl_xor(cm, 4, 8));
        float m_new = fmaxf(m, cm);
        float scale = __expf(m - m_new);
        float p = vA ? __expf(el - m_new) : 0.f;

        float ps = p;
        ps += __shfl_xor(ps, 1, 8);
        ps += __shfl_xor(ps, 2, 8);
        ps += __shfl_xor(ps, 4, 8);
        l = l * scale + ps;
        acc.x *= scale; acc.y *= scale; acc.z *= scale; acc.w *= scale;
        m = m_new;

        // 4. consume (branchless: invalid lanes have p=0, idx=0)
#pragma unroll
        for (int j = 0; j < 8; j++) {
            float pj  = __shfl(p, j, 8);
            float2 f01 = __half22float2(*(const __half2*)&u[j].x);
            float2 f23 = __half22float2(*(const __half2*)&u[j].y);
            acc.x += pj * f01.x; acc.y += pj * f01.y;
            acc.z += pj * f23.x; acc.w += pj * f23.y;
        }
        idxA = idxB; asA = asB; vA = vB;
    }

    float li = 1.f / (l + 1e-16f);
    float4 b4 = ((const float4*)bias)[tl];
    float4 o;
    o.x = fmaxf(acc.x * li + b4.x, 0.f);
    o.y = fmaxf(acc.y * li + b4.y, 0.f);
    o.z = fmaxf(acc.z * li + b4.z, 0.f);
    o.w = fmaxf(acc.w * li + b4.w, 0.f);
    ((float4*)out)[(size_t)node * GS + tl] = o;
}

// fp32 fused variant (layer 2, 1 head, GS=8), same R15 structure

template <int H_>
__global__ __launch_bounds__(256)
void gat_fused_kernel(const float* __restrict__ Hm,
                      const float* __restrict__ as_,
                      const float* __restrict__ ad_,
                      const int* __restrict__ rowptr,
                      const int* __restrict__ csr,
                      const float* __restrict__ bias,
                      float* __restrict__ out, int n) {
    constexpr int GS  = H_ * 8;
    constexpr int NPB = 256 / GS;
    int t = threadIdx.x;
    int node = blockIdx.x * NPB + t / GS;
    if (node >= n) return;
    int tl = t % GS;
    int h  = tl >> 3;
    int k8 = tl & 7;
    const float4* H4 = (const float4*)Hm;
    int e0 = rowptr[node], e1 = rowptr[node + 1];
    float ad_d = ad_[(size_t)node * H_ + h];

    int  ce  = e0 + k8;
    bool vA  = ce < e1;
    int  idxA = vA ? csr[ce] : 0;
    float asA = vA ? as_[(size_t)idxA * H_ + h] : 0.f;

    float m = -INFINITY, l = 0.f;
    float4 acc = make_float4(0.f, 0.f, 0.f, 0.f);

    for (int eb = e0; eb < e1; eb += 8) {
        // 1. issue this chunk's 8 row gathers
        float4 u[8];
#pragma unroll
        for (int j = 0; j < 8; j++) {
            int src = __shfl(idxA, j, 8);
            u[j] = H4[(size_t)src * GS + tl];
        }

        // 2. prefetch next chunk's idx + alpha_src
        int  ne  = eb + 8 + k8;
        bool vB  = ne < e1;
        int  idxB = vB ? csr[ne] : 0;
        float asB = vB ? as_[(size_t)idxB * H_ + h] : 0.f;

        // 3. softmax chain
        float el = asA + ad_d;
        el = (el > 0.f) ? el : NEG_SLOPE * el;
        el = vA ? el : -INFINITY;

        float cm = el;
        cm = fmaxf(cm, __shfl_xor(cm, 1, 8));
        cm = fmaxf(cm, __shfl_xor(cm, 2, 8));
        cm = fmaxf(cm, __shfl_xor(cm, 4, 8));
        float m_new = fmaxf(m, cm);
        float scale = __expf(m - m_new);
        float p = vA ? __expf(el - m_new) : 0.f;

        float ps = p;
        ps += __shfl_xor(ps, 1, 8);
        ps += __shfl_xor(ps, 2, 8);
        ps += __shfl_xor(ps, 4, 8);
        l = l * scale + ps;
        acc.x *= scale; acc.y *= scale; acc.z *= scale; acc.w *= scale;
        m = m_new;

        // 4. consume
#pragma unroll
        for (int j = 0; j < 8; j++) {
            float pj  = __shfl(p, j, 8);
            acc.x += pj * u[j].x; acc.y += pj * u[j].y;
            acc.z += pj * u[j].z; acc.w += pj * u[j].w;
        }
        idxA = idxB; asA = asB; vA = vB;
    }

    float li = 1.f / (l + 1e-16f);
    float4 b4 = ((const float4*)bias)[tl];
    float4 o;
    o.x = fmaxf(acc.x * li + b4.x, 0.f);
    o.y = fmaxf(acc.y * li + b4.y, 0.f);
    o.z = fmaxf(acc.z * li + b4.z, 0.f);
    o.w = fmaxf(acc.w * li + b4.w, 0.f);
    ((float4*)out)[(size_t)node * GS + tl] = o;
}

// ---------------- final linear: out[n,40] = X[n,32] @ lw[32,40] + lb -------

__global__ void final_linear_kernel(const float* __restrict__ X,
                                    const float* __restrict__ lw,
                                    const float* __restrict__ lb,
                                    float* __restrict__ out, int n) {
    int i = blockIdx.x * blockDim.x + threadIdx.x;
    if (i >= n * 40) return;
    int node = i / 40, cls = i % 40;
    const float* xp = X + (size_t)node * 32;
    float acc = lb[cls];
#pragma unroll
    for (int k = 0; k < 32; k++) acc += xp[k] * lw[k * 40 + cls];
    out[i] = acc;
}

// ---------------- launch ----------------

extern "C" void kernel_launch(void* const* d_in, const int* in_sizes, int n_in,
                              void* d_out, int out_size, void* d_ws, size_t ws_size,
                              hipStream_t stream) {
    const float* x   = (const float*)d_in[0];
    const int*   ei  = (const int*)d_in[1];
    const float* W0  = (const float*)d_in[2];
    const float* as0 = (const float*)d_in[3];
    const float* ad0 = (const float*)d_in[4];
    const float* b0  = (const float*)d_in[5];
    const float* W1  = (const float*)d_in[6];
    const float* as1 = (const float*)d_in[7];
    const float* ad1 = (const float*)d_in[8];
    const float* b1  = (const float*)d_in[9];
    const float* W2  = (const float*)d_in[10];
    const float* as2 = (const float*)d_in[11];
    const float* ad2 = (const float*)d_in[12];
    const float* b2  = (const float*)d_in[13];
    const float* lw  = (const float*)d_in[14];
    const float* lb  = (const float*)d_in[15];
    float* out = (float*)d_out;

    const int n    = in_sizes[0] / 128;   // 100000 (= 32 * 3125)
    const int eraw = in_sizes[1] / 2;     // 1600000
    const int etot = eraw + n;
    const int nb   = (n + 1023) / 1024;

    char* wsp = (char*)d_ws;
    size_t off = 0;
    auto alloc = [&](size_t bytes) -> void* {
        void* p = wsp + off;
        off += (bytes + 255) & ~(size_t)255;
        return p;
    };
    float*  hbuf   = (float*)alloc((size_t)n * 128 * 4);   // fp32 h (layer 2)
    float*  bufA   = (float*)alloc((size_t)n * 128 * 4);   // layer outputs
    __half* h16    = (__half*)alloc((size_t)n * 128 * 2);  // fp16 h (layers 0/1)
    float*  asb    = (float*)alloc((size_t)n * 4 * 4);
    float*  adb    = (float*)alloc((size_t)n * 4 * 4);
    int*    deg    = (int*)alloc((size_t)n * 4);
    int*    rank   = (int*)alloc((size_t)etot * 4);
    int*    rowptr = (int*)alloc((size_t)(n + 1) * 4);
    int*    csr    = (int*)alloc((size_t)etot * 4);
    int*    bsum   = (int*)alloc((size_t)nb * 4);
    int*    boffs  = (int*)alloc((size_t)nb * 4);

    // --- CSR build (single atomic pass) ---
    zero1_kernel<<<(n + 255) / 256, 256, 0, stream>>>(deg, n);
    count_rank_kernel<<<(etot + 255) / 256, 256, 0, stream>>>(ei, eraw, n, deg, rank);
    scan_local_kernel<<<nb, 1024, 0, stream>>>(deg, rowptr, bsum, n);
    scan_sums_kernel<<<1, 128, 0, stream>>>(bsum, boffs, nb);
    scan_add_kernel<<<(n + 255) / 256, 256, 0, stream>>>(rowptr, boffs, n, etot);
    scatter2_kernel<<<(etot + 255) / 256, 256, 0, stream>>>(ei, rank, eraw, n, rowptr, csr);

    // --- layer 0: 128 -> 4x32, concat (fp16 H) ---
    gemm_rt_f16_kernel<<<n / 32, 256, 0, stream>>>(x, W0, h16, n);
    attn_coef_f16_kernel<<<(n * 4 + 255) / 256, 256, 0, stream>>>(h16, as0, ad0, asb, adb, n);
    gat_fused_f16_kernel<<<(n + 7) / 8, 256, 0, stream>>>(h16, asb, adb, rowptr, csr, b0, bufA, n);

    // --- layer 1: 128 -> 4x32, concat (fp16 H) ---
    gemm_rt_f16_kernel<<<n / 32, 256, 0, stream>>>(bufA, W1, h16, n);
    attn_coef_f16_kernel<<<(n * 4 + 255) / 256, 256, 0, stream>>>(h16, as1, ad1, asb, adb, n);
    gat_fused_f16_kernel<<<(n + 7) / 8, 256, 0, stream>>>(h16, asb, adb, rowptr, csr, b1, bufA, n);

    // --- layer 2: 128 -> 1x32 (fp32 throughout) ---
    gemm_kernel<32, 8><<<(n + 7) / 8, 128, 0, stream>>>(bufA, W2, hbuf, n);
    attn_coef_kernel<1, 32><<<(n + 255) / 256, 256, 0, stream>>>(hbuf, as2, ad2, asb, adb, n);
    gat_fused_kernel<1><<<(n + 31) / 32, 256, 0, stream>>>(hbuf, asb, adb, rowptr, csr, b2, bufA, n);

    // --- final linear 32 -> 40 ---
    final_linear_kernel<<<(n * 40 + 255) / 256, 256, 0, stream>>>(bufA, lw, lb, out, n);
}

// Round 5
// 571.132 us; speedup vs baseline: 1.2330x; 1.0743x over previous
//
#include <hip/hip_runtime.h>
#include <hip/hip_bf16.h>
#include <hip/hip_fp16.h>
#include <math.h>

// ---------------------------------------------------------------------------
// GAT (3 layers, heads=4/4/1, hid=32) + final linear, fp32 compute.
// R16: fused gather kernels sit on a ~4 TB/s random-128B L2-fill wall
//      (R14/R15/R8 all plateau at 3.95 TB/s; FETCH ~= compulsory XCD
//      replication of the H table). Reduce reducible bytes instead:
//      - inter-layer activations (buf16) now fp16: fused kernels write fp16
//        (WRITE 50->25 MB each), GEMMs read fp16.
//      - layer-2 H table fp16 (gather demand 218->109 MB).
//      - final_linear fused into the layer-2 aggregation kernel (kills a
//        12.8 MB read + separate launch).
//      Precision: +~5e-4 relative per added fp16 rounding; expected absmax
//      ~2e-3 vs 6.015e-3 threshold.
// ---------------------------------------------------------------------------

#define NEG_SLOPE 0.2f

// ---------------- CSR build ----------------

__global__ void zero1_kernel(int* __restrict__ a, int n) {
    int i = blockIdx.x * blockDim.x + threadIdx.x;
    if (i < n) a[i] = 0;
}

__global__ void count_rank_kernel(const int* __restrict__ ei, int eraw, int n,
                                  int* __restrict__ deg, int* __restrict__ rank) {
    int i = blockIdx.x * blockDim.x + threadIdx.x;
    int etot = eraw + n;
    if (i >= etot) return;
    int dst = (i < eraw) ? ei[eraw + i] : (i - eraw);
    rank[i] = atomicAdd(&deg[dst], 1);
}

__global__ __launch_bounds__(1024)
void scan_local_kernel(const int* __restrict__ deg, int* __restrict__ rowptr,
                       int* __restrict__ bsum, int n) {
    __shared__ int buf[1024];
    int tid = threadIdx.x;
    int i = blockIdx.x * 1024 + tid;
    int v = (i < n) ? deg[i] : 0;
    buf[tid] = v;
    __syncthreads();
    for (int off = 1; off < 1024; off <<= 1) {
        int t = (tid >= off) ? buf[tid - off] : 0;
        __syncthreads();
        buf[tid] += t;
        __syncthreads();
    }
    if (i < n) rowptr[i] = buf[tid] - v;
    if (tid == 1023) bsum[blockIdx.x] = buf[1023];
}

__global__ __launch_bounds__(128)
void scan_sums_kernel(const int* __restrict__ bsum, int* __restrict__ boffs, int nb) {
    __shared__ int buf[128];
    int tid = threadIdx.x;
    int v = (tid < nb) ? bsum[tid] : 0;
    buf[tid] = v;
    __syncthreads();
    for (int off = 1; off < 128; off <<= 1) {
        int t = (tid >= off) ? buf[tid - off] : 0;
        __syncthreads();
        buf[tid] += t;
        __syncthreads();
    }
    if (tid < nb) boffs[tid] = buf[tid] - v;
}

__global__ void scan_add_kernel(int* __restrict__ rowptr, const int* __restrict__ boffs,
                                int n, int etot) {
    int i = blockIdx.x * blockDim.x + threadIdx.x;
    if (i < n) rowptr[i] += boffs[i >> 10];
    if (i == 0) rowptr[n] = etot;
}

__global__ void scatter2_kernel(const int* __restrict__ ei, const int* __restrict__ rank,
                                int eraw, int n, const int* __restrict__ rowptr,
                                int* __restrict__ csr_src) {
    int i = blockIdx.x * blockDim.x + threadIdx.x;
    int etot = eraw + n;
    if (i >= etot) return;
    int src, dst;
    if (i < eraw) { src = ei[i]; dst = ei[eraw + i]; }
    else          { src = i - eraw; dst = src; }
    csr_src[rowptr[dst] + rank[i]] = src;
}

// ---------------- register-tiled GEMM, fp16 output -------------------------
// H16[n,128] = X[n,128] @ W[128,128], stored as __half. n % 32 == 0.

struct h4pack { __half2 a, b; };   // 4 halves = 8 B

// fp32-input variant (layer 0)
__global__ __launch_bounds__(256)
void gemm_rt_f32in_kernel(const float* __restrict__ X, const float* __restrict__ W,
                          __half* __restrict__ H, int n) {
    __shared__ float xsT[128][36];
    int t = threadIdx.x;
    int base = blockIdx.x * 32;
    {
        int r  = t >> 3;
        int k0 = (t & 7) << 4;
        const float4* xp = (const float4*)(X + (size_t)(base + r) * 128 + k0);
        float4 a = xp[0], b = xp[1], c = xp[2], d = xp[3];
        xsT[k0 +  0][r] = a.x; xsT[k0 +  1][r] = a.y; xsT[k0 +  2][r] = a.z; xsT[k0 +  3][r] = a.w;
        xsT[k0 +  4][r] = b.x; xsT[k0 +  5][r] = b.y; xsT[k0 +  6][r] = b.z; xsT[k0 +  7][r] = b.w;
        xsT[k0 +  8][r] = c.x; xsT[k0 +  9][r] = c.y; xsT[k0 + 10][r] = c.z; xsT[k0 + 11][r] = c.w;
        xsT[k0 + 12][r] = d.x; xsT[k0 + 13][r] = d.y; xsT[k0 + 14][r] = d.z; xsT[k0 + 15][r] = d.w;
    }
    __syncthreads();

    int tx = t & 31;
    int ty = t >> 5;
    float4 acc0 = make_float4(0.f, 0.f, 0.f, 0.f);
    float4 acc1 = acc0, acc2 = acc0, acc3 = acc0;
    const float4* W4 = (const float4*)W;

#pragma unroll 4
    for (int k = 0; k < 128; k++) {
        float4 w  = W4[k * 32 + tx];
        float4 xv = *(const float4*)(&xsT[k][ty << 2]);
        acc0.x += xv.x * w.x; acc0.y += xv.x * w.y; acc0.z += xv.x * w.z; acc0.w += xv.x * w.w;
        acc1.x += xv.y * w.x; acc1.y += xv.y * w.y; acc1.z += xv.y * w.z; acc1.w += xv.y * w.w;
        acc2.x += xv.z * w.x; acc2.y += xv.z * w.y; acc2.z += xv.z * w.z; acc2.w += xv.z * w.w;
        acc3.x += xv.w * w.x; acc3.y += xv.w * w.y; acc3.z += xv.w * w.z; acc3.w += xv.w * w.w;
    }

    size_t row0 = (size_t)(base + (ty << 2));
    h4pack* hp = (h4pack*)(H + row0 * 128) + tx;      // row stride = 32 h4pack
    h4pack p;
    p.a = __floats2half2_rn(acc0.x, acc0.y); p.b = __floats2half2_rn(acc0.z, acc0.w);
    hp[0]  = p;
    p.a = __floats2half2_rn(acc1.x, acc1.y); p.b = __floats2half2_rn(acc1.z, acc1.w);
    hp[32] = p;
    p.a = __floats2half2_rn(acc2.x, acc2.y); p.b = __floats2half2_rn(acc2.z, acc2.w);
    hp[64] = p;
    p.a = __floats2half2_rn(acc3.x, acc3.y); p.b = __floats2half2_rn(acc3.z, acc3.w);
    hp[96] = p;
}

// fp16-input variant (layer 1)
__global__ __launch_bounds__(256)
void gemm_rt_f16in_kernel(const __half* __restrict__ X, const float* __restrict__ W,
                          __half* __restrict__ H, int n) {
    __shared__ float xsT[128][36];
    int t = threadIdx.x;
    int base = blockIdx.x * 32;
    {
        int r  = t >> 3;
        int k0 = (t & 7) << 4;
        const uint4* xp = (const uint4*)(X + (size_t)(base + r) * 128 + k0);  // 32 B = 16 halves
        uint4 a = xp[0], b = xp[1];
        float2 f;
        f = __half22float2(*(const __half2*)&a.x); xsT[k0 +  0][r] = f.x; xsT[k0 +  1][r] = f.y;
        f = __half22float2(*(const __half2*)&a.y); xsT[k0 +  2][r] = f.x; xsT[k0 +  3][r] = f.y;
        f = __half22float2(*(const __half2*)&a.z); xsT[k0 +  4][r] = f.x; xsT[k0 +  5][r] = f.y;
        f = __half22float2(*(const __half2*)&a.w); xsT[k0 +  6][r] = f.x; xsT[k0 +  7][r] = f.y;
        f = __half22float2(*(const __half2*)&b.x); xsT[k0 +  8][r] = f.x; xsT[k0 +  9][r] = f.y;
        f = __half22float2(*(const __half2*)&b.y); xsT[k0 + 10][r] = f.x; xsT[k0 + 11][r] = f.y;
        f = __half22float2(*(const __half2*)&b.z); xsT[k0 + 12][r] = f.x; xsT[k0 + 13][r] = f.y;
        f = __half22float2(*(const __half2*)&b.w); xsT[k0 + 14][r] = f.x; xsT[k0 + 15][r] = f.y;
    }
    __syncthreads();

    int tx = t & 31;
    int ty = t >> 5;
    float4 acc0 = make_float4(0.f, 0.f, 0.f, 0.f);
    float4 acc1 = acc0, acc2 = acc0, acc3 = acc0;
    const float4* W4 = (const float4*)W;

#pragma unroll 4
    for (int k = 0; k < 128; k++) {
        float4 w  = W4[k * 32 + tx];
        float4 xv = *(const float4*)(&xsT[k][ty << 2]);
        acc0.x += xv.x * w.x; acc0.y += xv.x * w.y; acc0.z += xv.x * w.z; acc0.w += xv.x * w.w;
        acc1.x += xv.y * w.x; acc1.y += xv.y * w.y; acc1.z += xv.y * w.z; acc1.w += xv.y * w.w;
        acc2.x += xv.z * w.x; acc2.y += xv.z * w.y; acc2.z += xv.z * w.z; acc2.w += xv.z * w.w;
        acc3.x += xv.w * w.x; acc3.y += xv.w * w.y; acc3.z += xv.w * w.z; acc3.w += xv.w * w.w;
    }

    size_t row0 = (size_t)(base + (ty << 2));
    h4pack* hp = (h4pack*)(H + row0 * 128) + tx;
    h4pack p;
    p.a = __floats2half2_rn(acc0.x, acc0.y); p.b = __floats2half2_rn(acc0.z, acc0.w);
    hp[0]  = p;
    p.a = __floats2half2_rn(acc1.x, acc1.y); p.b = __floats2half2_rn(acc1.z, acc1.w);
    hp[32] = p;
    p.a = __floats2half2_rn(acc2.x, acc2.y); p.b = __floats2half2_rn(acc2.z, acc2.w);
    hp[64] = p;
    p.a = __floats2half2_rn(acc3.x, acc3.y); p.b = __floats2half2_rn(acc3.z, acc3.w);
    hp[96] = p;
}

// ---------------- layer-2 GEMM: [n,128] fp16 @ [128,32] -> [n,32] fp16 -----

__global__ __launch_bounds__(128)
void gemm_l2_f16_kernel(const __half* __restrict__ X, const float* __restrict__ W,
                        __half* __restrict__ H, int n) {
    __shared__ float xs[8][129];
    int base = blockIdx.x * 8;
    int tid = threadIdx.x;
#pragma unroll
    for (int it = 0; it < 4; it++) {
        int i = tid + it * 128;          // 0..511 half2 elements
        int r = i >> 6, c2 = i & 63;
        int row = base + r;
        __half2 v = (row < n) ? ((const __half2*)(X + (size_t)row * 128))[c2]
                              : __floats2half2_rn(0.f, 0.f);
        float2 f = __half22float2(v);
        xs[r][c2 * 2] = f.x; xs[r][c2 * 2 + 1] = f.y;
    }
    __syncthreads();
    int col  = tid & 31;
    int rsub = tid >> 5;                 // 0..3
    float acc0 = 0.f, acc1 = 0.f;
    for (int k = 0; k < 128; k++) {
        float w = W[k * 32 + col];
        acc0 += xs[rsub][k] * w;
        acc1 += xs[rsub + 4][k] * w;
    }
    int row0 = base + rsub;
    if (row0 < n)     H[(size_t)row0 * 32 + col]       = __float2half(acc0);
    if (row0 + 4 < n) H[(size_t)(row0 + 4) * 32 + col] = __float2half(acc1);
}

// ---------------- attention coefficients (fp16 H) --------------------------

__global__ void attn_coef_f16_kernel(const __half* __restrict__ H,
                                     const float* __restrict__ a_s,
                                     const float* __restrict__ a_d,
                                     float* __restrict__ as_out,
                                     float* __restrict__ ad_out, int n) {
    int i = blockIdx.x * blockDim.x + threadIdx.x;
    if (i >= n * 4) return;
    int node = i >> 2, h = i & 3;
    const __half2* hp = (const __half2*)(H + (size_t)node * 128 + h * 32);
    float s = 0.f, d = 0.f;
#pragma unroll
    for (int c2 = 0; c2 < 16; c2++) {
        float2 v = __half22float2(hp[c2]);
        s += v.x * a_s[h * 32 + c2 * 2] + v.y * a_s[h * 32 + c2 * 2 + 1];
        d += v.x * a_d[h * 32 + c2 * 2] + v.y * a_d[h * 32 + c2 * 2 + 1];
    }
    as_out[i] = s;
    ad_out[i] = d;
}

// layer-2 variant: 1 head, 32 channels, fp16 H
__global__ void attn_coef_l2_f16_kernel(const __half* __restrict__ H,
                                        const float* __restrict__ a_s,
                                        const float* __restrict__ a_d,
                                        float* __restrict__ as_out,
                                        float* __restrict__ ad_out, int n) {
    int i = blockIdx.x * blockDim.x + threadIdx.x;
    if (i >= n) return;
    const __half2* hp = (const __half2*)(H + (size_t)i * 32);
    float s = 0.f, d = 0.f;
#pragma unroll
    for (int c2 = 0; c2 < 16; c2++) {
        float2 v = __half22float2(hp[c2]);
        s += v.x * a_s[2 * c2] + v.y * a_s[2 * c2 + 1];
        d += v.x * a_d[2 * c2] + v.y * a_d[2 * c2 + 1];
    }
    as_out[i] = s;
    ad_out[i] = d;
}

// ---------------- fused online-softmax aggregation, fp16 gathers -----------
// 4 heads, GS=32 lanes/node; lane tl covers channels 4tl..4tl+3 (8 B fp16).
// R16: output written fp16 (h4pack).

__global__ __launch_bounds__(256)
void gat_fused_f16_kernel(const __half* __restrict__ Hm,
                          const float* __restrict__ as_,
                          const float* __restrict__ ad_,
                          const int* __restrict__ rowptr,
                          const int* __restrict__ csr,
                          const float* __restrict__ bias,
                          __half* __restrict__ out, int n) {
    constexpr int GS = 32;
    int t = threadIdx.x;
    int node = blockIdx.x * 8 + (t >> 5);
    if (node >= n) return;
    int tl = t & 31;
    int h  = tl >> 3;
    int k8 = tl & 7;
    const uint2* H8 = (const uint2*)Hm;     // 8 B = 4 halves per lane
    int e0 = rowptr[node], e1 = rowptr[node + 1];
    float ad_d = ad_[(size_t)node * 4 + h];

    int  ce  = e0 + k8;
    bool vA  = ce < e1;
    int  idxA = vA ? csr[ce] : 0;
    float asA = vA ? as_[(size_t)idxA * 4 + h] : 0.f;

    float m = -INFINITY, l = 0.f;
    float4 acc = make_float4(0.f, 0.f, 0.f, 0.f);

    for (int eb = e0; eb < e1; eb += 8) {
        uint2 u[8];
#pragma unroll
        for (int j = 0; j < 8; j++) {
            int src = __shfl(idxA, j, 8);
            u[j] = H8[(size_t)src * GS + tl];
        }

        int  ne  = eb + 8 + k8;
        bool vB  = ne < e1;
        int  idxB = vB ? csr[ne] : 0;
        float asB = vB ? as_[(size_t)idxB * 4 + h] : 0.f;

        float el = asA + ad_d;
        el = (el > 0.f) ? el : NEG_SLOPE * el;
        el = vA ? el : -INFINITY;

        float cm = el;
        cm = fmaxf(cm, __shfl_xor(cm, 1, 8));
        cm = fmaxf(cm, __shfl_xor(cm, 2, 8));
        cm = fmaxf(cm, __shfl_xor(cm, 4, 8));
        float m_new = fmaxf(m, cm);
        float scale = __expf(m - m_new);
        float p = vA ? __expf(el - m_new) : 0.f;

        float ps = p;
        ps += __shfl_xor(ps, 1, 8);
        ps += __shfl_xor(ps, 2, 8);
        ps += __shfl_xor(ps, 4, 8);
        l = l * scale + ps;
        acc.x *= scale; acc.y *= scale; acc.z *= scale; acc.w *= scale;
        m = m_new;

#pragma unroll
        for (int j = 0; j < 8; j++) {
            float pj  = __shfl(p, j, 8);
            float2 f01 = __half22float2(*(const __half2*)&u[j].x);
            float2 f23 = __half22float2(*(const __half2*)&u[j].y);
            acc.x += pj * f01.x; acc.y += pj * f01.y;
            acc.z += pj * f23.x; acc.w += pj * f23.y;
        }
        idxA = idxB; asA = asB; vA = vB;
    }

    float li = 1.f / (l + 1e-16f);
    float4 b4 = ((const float4*)bias)[tl];
    float4 o;
    o.x = fmaxf(acc.x * li + b4.x, 0.f);
    o.y = fmaxf(acc.y * li + b4.y, 0.f);
    o.z = fmaxf(acc.z * li + b4.z, 0.f);
    o.w = fmaxf(acc.w * li + b4.w, 0.f);
    h4pack po;
    po.a = __floats2half2_rn(o.x, o.y);
    po.b = __floats2half2_rn(o.z, o.w);
    ((h4pack*)out)[(size_t)node * 32 + tl] = po;
}

// ---------------- layer-2 fused: fp16 gathers + bias/relu + final linear ---
// 1 head, GS=8 lanes/node; lane tl covers channels 4tl..4tl+3 (8 B fp16).
// After aggregation, the 8-lane group computes out[node,40] = relu(o)@lw + lb
// via intra-group shuffles (lane tl handles classes tl, tl+8, ..., tl+32).

__global__ __launch_bounds__(256)
void gat_fused_l2_kernel(const __half* __restrict__ Hm,
                         const float* __restrict__ as_,
                         const float* __restrict__ ad_,
                         const int* __restrict__ rowptr,
                         const int* __restrict__ csr,
                         const float* __restrict__ bias,
                         const float* __restrict__ lw,
                         const float* __restrict__ lb,
                         float* __restrict__ out, int n) {
    int t = threadIdx.x;
    int node = blockIdx.x * 32 + (t >> 3);
    if (node >= n) return;
    int tl = t & 7;
    const uint2* H8 = (const uint2*)Hm;     // row = 8 uint2 (32 halves)
    int e0 = rowptr[node], e1 = rowptr[node + 1];
    float ad_d = ad_[node];

    int  ce  = e0 + tl;
    bool vA  = ce < e1;
    int  idxA = vA ? csr[ce] : 0;
    float asA = vA ? as_[idxA] : 0.f;

    float m = -INFINITY, l = 0.f;
    float4 acc = make_float4(0.f, 0.f, 0.f, 0.f);

    for (int eb = e0; eb < e1; eb += 8) {
        uint2 u[8];
#pragma unroll
        for (int j = 0; j < 8; j++) {
            int src = __shfl(idxA, j, 8);
            u[j] = H8[(size_t)src * 8 + tl];
        }

        int  ne  = eb + 8 + tl;
        bool vB  = ne < e1;
        int  idxB = vB ? csr[ne] : 0;
        float asB = vB ? as_[idxB] : 0.f;

        float el = asA + ad_d;
        el = (el > 0.f) ? el : NEG_SLOPE * el;
        el = vA ? el : -INFINITY;

        float cm = el;
        cm = fmaxf(cm, __shfl_xor(cm, 1, 8));
        cm = fmaxf(cm, __shfl_xor(cm, 2, 8));
        cm = fmaxf(cm, __shfl_xor(cm, 4, 8));
        float m_new = fmaxf(m, cm);
        float scale = __expf(m - m_new);
        float p = vA ? __expf(el - m_new) : 0.f;

        float ps = p;
        ps += __shfl_xor(ps, 1, 8);
        ps += __shfl_xor(ps, 2, 8);
        ps += __shfl_xor(ps, 4, 8);
        l = l * scale + ps;
        acc.x *= scale; acc.y *= scale; acc.z *= scale; acc.w *= scale;
        m = m_new;

#pragma unroll
        for (int j = 0; j < 8; j++) {
            float pj  = __shfl(p, j, 8);
            float2 f01 = __half22float2(*(const __half2*)&u[j].x);
            float2 f23 = __half22float2(*(const __half2*)&u[j].y);
            acc.x += pj * f01.x; acc.y += pj * f01.y;
            acc.z += pj * f23.x; acc.w += pj * f23.y;
        }
        idxA = idxB; asA = asB; vA = vB;
    }

    float li = 1.f / (l + 1e-16f);
    float4 b4 = ((const float4*)bias)[tl];
    float4 o;
    o.x = fmaxf(acc.x * li + b4.x, 0.f);
    o.y = fmaxf(acc.y * li + b4.y, 0.f);
    o.z = fmaxf(acc.z * li + b4.z, 0.f);
    o.w = fmaxf(acc.w * li + b4.w, 0.f);

    // fused final linear: lane tl computes classes tl + 8c (c = 0..4)
    float fin0 = lb[tl];
    float fin1 = lb[tl + 8];
    float fin2 = lb[tl + 16];
    float fin3 = lb[tl + 24];
    float fin4 = lb[tl + 32];
#pragma unroll
    for (int j = 0; j < 8; j++) {
        float vx = __shfl(o.x, j, 8);
        float vy = __shfl(o.y, j, 8);
        float vz = __shfl(o.z, j, 8);
        float vw = __shfl(o.w, j, 8);
        const float* l0 = lw + (size_t)(4 * j) * 40;   // rows 4j..4j+3 of lw[32,40]
#pragma unroll
        for (int c = 0; c < 5; c++) {
            int cls = tl + 8 * c;
            float v = vx * l0[cls] + vy * l0[40 + cls] + vz * l0[80 + cls] + vw * l0[120 + cls];
            if (c == 0) fin0 += v;
            else if (c == 1) fin1 += v;
            else if (c == 2) fin2 += v;
            else if (c == 3) fin3 += v;
            else fin4 += v;
        }
    }
    float* op = out + (size_t)node * 40;
    op[tl]      = fin0;
    op[tl + 8]  = fin1;
    op[tl + 16] = fin2;
    op[tl + 24] = fin3;
    op[tl + 32] = fin4;
}

// ---------------- launch ----------------

extern "C" void kernel_launch(void* const* d_in, const int* in_sizes, int n_in,
                              void* d_out, int out_size, void* d_ws, size_t ws_size,
                              hipStream_t stream) {
    const float* x   = (const float*)d_in[0];
    const int*   ei  = (const int*)d_in[1];
    const float* W0  = (const float*)d_in[2];
    const float* as0 = (const float*)d_in[3];
    const float* ad0 = (const float*)d_in[4];
    const float* b0  = (const float*)d_in[5];
    const float* W1  = (const float*)d_in[6];
    const float* as1 = (const float*)d_in[7];
    const float* ad1 = (const float*)d_in[8];
    const float* b1  = (const float*)d_in[9];
    const float* W2  = (const float*)d_in[10];
    const float* as2 = (const float*)d_in[11];
    const float* ad2 = (const float*)d_in[12];
    const float* b2  = (const float*)d_in[13];
    const float* lw  = (const float*)d_in[14];
    const float* lb  = (const float*)d_in[15];
    float* out = (float*)d_out;

    const int n    = in_sizes[0] / 128;   // 100000 (= 32 * 3125)
    const int eraw = in_sizes[1] / 2;     // 1600000
    const int etot = eraw + n;
    const int nb   = (n + 1023) / 1024;

    char* wsp = (char*)d_ws;
    size_t off = 0;
    auto alloc = [&](size_t bytes) -> void* {
        void* p = wsp + off;
        off += (bytes + 255) & ~(size_t)255;
        return p;
    };
    __half* h16    = (__half*)alloc((size_t)n * 128 * 2);  // per-layer h table
    __half* buf16  = (__half*)alloc((size_t)n * 128 * 2);  // inter-layer activations
    __half* h2     = (__half*)alloc((size_t)n * 32 * 2);   // layer-2 h table
    float*  asb    = (float*)alloc((size_t)n * 4 * 4);
    float*  adb    = (float*)alloc((size_t)n * 4 * 4);
    int*    deg    = (int*)alloc((size_t)n * 4);
    int*    rank   = (int*)alloc((size_t)etot * 4);
    int*    rowptr = (int*)alloc((size_t)(n + 1) * 4);
    int*    csr    = (int*)alloc((size_t)etot * 4);
    int*    bsum   = (int*)alloc((size_t)nb * 4);
    int*    boffs  = (int*)alloc((size_t)nb * 4);

    // --- CSR build (single atomic pass) ---
    zero1_kernel<<<(n + 255) / 256, 256, 0, stream>>>(deg, n);
    count_rank_kernel<<<(etot + 255) / 256, 256, 0, stream>>>(ei, eraw, n, deg, rank);
    scan_local_kernel<<<nb, 1024, 0, stream>>>(deg, rowptr, bsum, n);
    scan_sums_kernel<<<1, 128, 0, stream>>>(bsum, boffs, nb);
    scan_add_kernel<<<(n + 255) / 256, 256, 0, stream>>>(rowptr, boffs, n, etot);
    scatter2_kernel<<<(etot + 255) / 256, 256, 0, stream>>>(ei, rank, eraw, n, rowptr, csr);

    // --- layer 0: 128 -> 4x32, concat ---
    gemm_rt_f32in_kernel<<<n / 32, 256, 0, stream>>>(x, W0, h16, n);
    attn_coef_f16_kernel<<<(n * 4 + 255) / 256, 256, 0, stream>>>(h16, as0, ad0, asb, adb, n);
    gat_fused_f16_kernel<<<(n + 7) / 8, 256, 0, stream>>>(h16, asb, adb, rowptr, csr, b0, buf16, n);

    // --- layer 1: 128 -> 4x32, concat ---
    gemm_rt_f16in_kernel<<<n / 32, 256, 0, stream>>>(buf16, W1, h16, n);
    attn_coef_f16_kernel<<<(n * 4 + 255) / 256, 256, 0, stream>>>(h16, as1, ad1, asb, adb, n);
    gat_fused_f16_kernel<<<(n + 7) / 8, 256, 0, stream>>>(h16, asb, adb, rowptr, csr, b1, buf16, n);

    // --- layer 2: 128 -> 1x32, + fused final linear ---
    gemm_l2_f16_kernel<<<(n + 7) / 8, 128, 0, stream>>>(buf16, W2, h2, n);
    attn_coef_l2_f16_kernel<<<(n + 255) / 256, 256, 0, stream>>>(h2, as2, ad2, asb, adb, n);
    gat_fused_l2_kernel<<<(n + 31) / 32, 256, 0, stream>>>(h2, asb, adb, rowptr, csr, b2, lw, lb, out, n);
}

// Round 6
// 528.810 us; speedup vs baseline: 1.3317x; 1.0800x over previous
//
#include <hip/hip_runtime.h>
#include <hip/hip_bf16.h>
#include <hip/hip_fp16.h>
#include <math.h>

// ---------------------------------------------------------------------------
// GAT (3 layers, heads=4/4/1, hid=32) + final linear.
// R17: dense 128x128 GEMMs (layers 0/1) moved to fp16 MFMA (16x16x32).
//      R16 counters showed gemm_rt_f32in = 73us with 2.8M LDS bank conflicts
//      and 1.6 GB of per-thread W re-reads from L1/L2; MFMA version has no
//      LDS, streams X once, W pre-transposed to fp16 Wt[c][k] (32 KB,
//      L1-resident). Fragment layouts per verified m89 mapping:
//      A: row=lane&15, k=(lane>>4)*8+j; B from Wt row c; D: col=lane&15,
//      row=(lane>>4)*4+reg. Everything else unchanged from R16.
// ---------------------------------------------------------------------------

#define NEG_SLOPE 0.2f

typedef __attribute__((ext_vector_type(8))) _Float16 f16x8;
typedef __attribute__((ext_vector_type(4))) float    f32x4;

// ---------------- CSR build ----------------

__global__ void zero1_kernel(int* __restrict__ a, int n) {
    int i = blockIdx.x * blockDim.x + threadIdx.x;
    if (i < n) a[i] = 0;
}

__global__ void count_rank_kernel(const int* __restrict__ ei, int eraw, int n,
                                  int* __restrict__ deg, int* __restrict__ rank) {
    int i = blockIdx.x * blockDim.x + threadIdx.x;
    int etot = eraw + n;
    if (i >= etot) return;
    int dst = (i < eraw) ? ei[eraw + i] : (i - eraw);
    rank[i] = atomicAdd(&deg[dst], 1);
}

__global__ __launch_bounds__(1024)
void scan_local_kernel(const int* __restrict__ deg, int* __restrict__ rowptr,
                       int* __restrict__ bsum, int n) {
    __shared__ int buf[1024];
    int tid = threadIdx.x;
    int i = blockIdx.x * 1024 + tid;
    int v = (i < n) ? deg[i] : 0;
    buf[tid] = v;
    __syncthreads();
    for (int off = 1; off < 1024; off <<= 1) {
        int t = (tid >= off) ? buf[tid - off] : 0;
        __syncthreads();
        buf[tid] += t;
        __syncthreads();
    }
    if (i < n) rowptr[i] = buf[tid] - v;
    if (tid == 1023) bsum[blockIdx.x] = buf[1023];
}

__global__ __launch_bounds__(128)
void scan_sums_kernel(const int* __restrict__ bsum, int* __restrict__ boffs, int nb) {
    __shared__ int buf[128];
    int tid = threadIdx.x;
    int v = (tid < nb) ? bsum[tid] : 0;
    buf[tid] = v;
    __syncthreads();
    for (int off = 1; off < 128; off <<= 1) {
        int t = (tid >= off) ? buf[tid - off] : 0;
        __syncthreads();
        buf[tid] += t;
        __syncthreads();
    }
    if (tid < nb) boffs[tid] = buf[tid] - v;
}

__global__ void scan_add_kernel(int* __restrict__ rowptr, const int* __restrict__ boffs,
                                int n, int etot) {
    int i = blockIdx.x * blockDim.x + threadIdx.x;
    if (i < n) rowptr[i] += boffs[i >> 10];
    if (i == 0) rowptr[n] = etot;
}

__global__ void scatter2_kernel(const int* __restrict__ ei, const int* __restrict__ rank,
                                int eraw, int n, const int* __restrict__ rowptr,
                                int* __restrict__ csr_src) {
    int i = blockIdx.x * blockDim.x + threadIdx.x;
    int etot = eraw + n;
    if (i >= etot) return;
    int src, dst;
    if (i < eraw) { src = ei[i]; dst = ei[eraw + i]; }
    else          { src = i - eraw; dst = src; }
    csr_src[rowptr[dst] + rank[i]] = src;
}

// ---------------- W -> fp16 transposed (Wt[c][k] = W[k][c]) ----------------

__global__ void wt_f16_kernel(const float* __restrict__ W, __half* __restrict__ Wt) {
    int i = blockIdx.x * blockDim.x + threadIdx.x;   // 16384
    int k = i >> 7, c = i & 127;
    Wt[c * 128 + k] = __float2half(W[i]);
}

// ---------------- MFMA GEMM: H16[n,128] = X[n,128] @ W  (fp16 in/out) ------
// Block = 256 threads = 4 waves; wave w handles rows blockIdx*64 + w*16.
// Per wave: full 128 output cols (8 col-tiles), K=128 in 4 MFMA k-steps.

__global__ __launch_bounds__(256)
void gemm_mfma_f32in_kernel(const float* __restrict__ X, const __half* __restrict__ Wt,
                            __half* __restrict__ H, int n) {
    int t = threadIdx.x;
    int wave = t >> 6, lane = t & 63;
    int l15 = lane & 15;
    int kg  = lane >> 4;                 // 0..3
    int base = blockIdx.x * 64 + wave * 16;
    int row  = base + l15;
    int rowc = (row < n) ? row : 0;      // clamp (store is guarded)

    f32x4 acc[8];
#pragma unroll
    for (int i = 0; i < 8; i++) acc[i] = (f32x4){0.f, 0.f, 0.f, 0.f};

    const float* xp = X + (size_t)rowc * 128 + kg * 8;
#pragma unroll
    for (int ks = 0; ks < 4; ks++) {
        float4 x0 = *(const float4*)(xp + ks * 32);
        float4 x1 = *(const float4*)(xp + ks * 32 + 4);
        f16x8 a;
        a[0] = (_Float16)x0.x; a[1] = (_Float16)x0.y; a[2] = (_Float16)x0.z; a[3] = (_Float16)x0.w;
        a[4] = (_Float16)x1.x; a[5] = (_Float16)x1.y; a[6] = (_Float16)x1.z; a[7] = (_Float16)x1.w;
#pragma unroll
        for (int ct = 0; ct < 8; ct++) {
            f16x8 b = *(const f16x8*)(Wt + (size_t)(ct * 16 + l15) * 128 + ks * 32 + kg * 8);
            acc[ct] = __builtin_amdgcn_mfma_f32_16x16x32_f16(a, b, acc[ct], 0, 0, 0);
        }
    }

    // D: col = lane&15, row = (lane>>4)*4 + reg
#pragma unroll
    for (int ct = 0; ct < 8; ct++) {
#pragma unroll
        for (int r = 0; r < 4; r++) {
            int orow = base + kg * 4 + r;
            if (orow < n)
                H[(size_t)orow * 128 + ct * 16 + l15] = __float2half(acc[ct][r]);
        }
    }
}

__global__ __launch_bounds__(256)
void gemm_mfma_f16in_kernel(const __half* __restrict__ X, const __half* __restrict__ Wt,
                            __half* __restrict__ H, int n) {
    int t = threadIdx.x;
    int wave = t >> 6, lane = t & 63;
    int l15 = lane & 15;
    int kg  = lane >> 4;
    int base = blockIdx.x * 64 + wave * 16;
    int row  = base + l15;
    int rowc = (row < n) ? row : 0;

    f32x4 acc[8];
#pragma unroll
    for (int i = 0; i < 8; i++) acc[i] = (f32x4){0.f, 0.f, 0.f, 0.f};

    const __half* xp = X + (size_t)rowc * 128 + kg * 8;
#pragma unroll
    for (int ks = 0; ks < 4; ks++) {
        f16x8 a = *(const f16x8*)(xp + ks * 32);
#pragma unroll
        for (int ct = 0; ct < 8; ct++) {
            f16x8 b = *(const f16x8*)(Wt + (size_t)(ct * 16 + l15) * 128 + ks * 32 + kg * 8);
            acc[ct] = __builtin_amdgcn_mfma_f32_16x16x32_f16(a, b, acc[ct], 0, 0, 0);
        }
    }

#pragma unroll
    for (int ct = 0; ct < 8; ct++) {
#pragma unroll
        for (int r = 0; r < 4; r++) {
            int orow = base + kg * 4 + r;
            if (orow < n)
                H[(size_t)orow * 128 + ct * 16 + l15] = __float2half(acc[ct][r]);
        }
    }
}

// ---------------- layer-2 GEMM: [n,128] fp16 @ [128,32] -> [n,32] fp16 -----

__global__ __launch_bounds__(128)
void gemm_l2_f16_kernel(const __half* __restrict__ X, const float* __restrict__ W,
                        __half* __restrict__ H, int n) {
    __shared__ float xs[8][129];
    int base = blockIdx.x * 8;
    int tid = threadIdx.x;
#pragma unroll
    for (int it = 0; it < 4; it++) {
        int i = tid + it * 128;          // 0..511 half2 elements
        int r = i >> 6, c2 = i & 63;
        int row = base + r;
        __half2 v = (row < n) ? ((const __half2*)(X + (size_t)row * 128))[c2]
                              : __floats2half2_rn(0.f, 0.f);
        float2 f = __half22float2(v);
        xs[r][c2 * 2] = f.x; xs[r][c2 * 2 + 1] = f.y;
    }
    __syncthreads();
    int col  = tid & 31;
    int rsub = tid >> 5;                 // 0..3
    float acc0 = 0.f, acc1 = 0.f;
    for (int k = 0; k < 128; k++) {
        float w = W[k * 32 + col];
        acc0 += xs[rsub][k] * w;
        acc1 += xs[rsub + 4][k] * w;
    }
    int row0 = base + rsub;
    if (row0 < n)     H[(size_t)row0 * 32 + col]       = __float2half(acc0);
    if (row0 + 4 < n) H[(size_t)(row0 + 4) * 32 + col] = __float2half(acc1);
}

// ---------------- attention coefficients (fp16 H) --------------------------

__global__ void attn_coef_f16_kernel(const __half* __restrict__ H,
                                     const float* __restrict__ a_s,
                                     const float* __restrict__ a_d,
                                     float* __restrict__ as_out,
                                     float* __restrict__ ad_out, int n) {
    int i = blockIdx.x * blockDim.x + threadIdx.x;
    if (i >= n * 4) return;
    int node = i >> 2, h = i & 3;
    const __half2* hp = (const __half2*)(H + (size_t)node * 128 + h * 32);
    float s = 0.f, d = 0.f;
#pragma unroll
    for (int c2 = 0; c2 < 16; c2++) {
        float2 v = __half22float2(hp[c2]);
        s += v.x * a_s[h * 32 + c2 * 2] + v.y * a_s[h * 32 + c2 * 2 + 1];
        d += v.x * a_d[h * 32 + c2 * 2] + v.y * a_d[h * 32 + c2 * 2 + 1];
    }
    as_out[i] = s;
    ad_out[i] = d;
}

// layer-2 variant: 1 head, 32 channels, fp16 H
__global__ void attn_coef_l2_f16_kernel(const __half* __restrict__ H,
                                        const float* __restrict__ a_s,
                                        const float* __restrict__ a_d,
                                        float* __restrict__ as_out,
                                        float* __restrict__ ad_out, int n) {
    int i = blockIdx.x * blockDim.x + threadIdx.x;
    if (i >= n) return;
    const __half2* hp = (const __half2*)(H + (size_t)i * 32);
    float s = 0.f, d = 0.f;
#pragma unroll
    for (int c2 = 0; c2 < 16; c2++) {
        float2 v = __half22float2(hp[c2]);
        s += v.x * a_s[2 * c2] + v.y * a_s[2 * c2 + 1];
        d += v.x * a_d[2 * c2] + v.y * a_d[2 * c2 + 1];
    }
    as_out[i] = s;
    ad_out[i] = d;
}

// ---------------- fused online-softmax aggregation, fp16 gathers -----------

struct h4pack { __half2 a, b; };   // 4 halves = 8 B

__global__ __launch_bounds__(256)
void gat_fused_f16_kernel(const __half* __restrict__ Hm,
                          const float* __restrict__ as_,
                          const float* __restrict__ ad_,
                          const int* __restrict__ rowptr,
                          const int* __restrict__ csr,
                          const float* __restrict__ bias,
                          __half* __restrict__ out, int n) {
    constexpr int GS = 32;
    int t = threadIdx.x;
    int node = blockIdx.x * 8 + (t >> 5);
    if (node >= n) return;
    int tl = t & 31;
    int h  = tl >> 3;
    int k8 = tl & 7;
    const uint2* H8 = (const uint2*)Hm;     // 8 B = 4 halves per lane
    int e0 = rowptr[node], e1 = rowptr[node + 1];
    float ad_d = ad_[(size_t)node * 4 + h];

    int  ce  = e0 + k8;
    bool vA  = ce < e1;
    int  idxA = vA ? csr[ce] : 0;
    float asA = vA ? as_[(size_t)idxA * 4 + h] : 0.f;

    float m = -INFINITY, l = 0.f;
    float4 acc = make_float4(0.f, 0.f, 0.f, 0.f);

    for (int eb = e0; eb < e1; eb += 8) {
        uint2 u[8];
#pragma unroll
        for (int j = 0; j < 8; j++) {
            int src = __shfl(idxA, j, 8);
            u[j] = H8[(size_t)src * GS + tl];
        }

        int  ne  = eb + 8 + k8;
        bool vB  = ne < e1;
        int  idxB = vB ? csr[ne] : 0;
        float asB = vB ? as_[(size_t)idxB * 4 + h] : 0.f;

        float el = asA + ad_d;
        el = (el > 0.f) ? el : NEG_SLOPE * el;
        el = vA ? el : -INFINITY;

        float cm = el;
        cm = fmaxf(cm, __shfl_xor(cm, 1, 8));
        cm = fmaxf(cm, __shfl_xor(cm, 2, 8));
        cm = fmaxf(cm, __shfl_xor(cm, 4, 8));
        float m_new = fmaxf(m, cm);
        float scale = __expf(m - m_new);
        float p = vA ? __expf(el - m_new) : 0.f;

        float ps = p;
        ps += __shfl_xor(ps, 1, 8);
        ps += __shfl_xor(ps, 2, 8);
        ps += __shfl_xor(ps, 4, 8);
        l = l * scale + ps;
        acc.x *= scale; acc.y *= scale; acc.z *= scale; acc.w *= scale;
        m = m_new;

#pragma unroll
        for (int j = 0; j < 8; j++) {
            float pj  = __shfl(p, j, 8);
            float2 f01 = __half22float2(*(const __half2*)&u[j].x);
            float2 f23 = __half22float2(*(const __half2*)&u[j].y);
            acc.x += pj * f01.x; acc.y += pj * f01.y;
            acc.z += pj * f23.x; acc.w += pj * f23.y;
        }
        idxA = idxB; asA = asB; vA = vB;
    }

    float li = 1.f / (l + 1e-16f);
    float4 b4 = ((const float4*)bias)[tl];
    float4 o;
    o.x = fmaxf(acc.x * li + b4.x, 0.f);
    o.y = fmaxf(acc.y * li + b4.y, 0.f);
    o.z = fmaxf(acc.z * li + b4.z, 0.f);
    o.w = fmaxf(acc.w * li + b4.w, 0.f);
    h4pack po;
    po.a = __floats2half2_rn(o.x, o.y);
    po.b = __floats2half2_rn(o.z, o.w);
    ((h4pack*)out)[(size_t)node * 32 + tl] = po;
}

// ---------------- layer-2 fused: fp16 gathers + bias/relu + final linear ---

__global__ __launch_bounds__(256)
void gat_fused_l2_kernel(const __half* __restrict__ Hm,
                         const float* __restrict__ as_,
                         const float* __restrict__ ad_,
                         const int* __restrict__ rowptr,
                         const int* __restrict__ csr,
                         const float* __restrict__ bias,
                         const float* __restrict__ lw,
                         const float* __restrict__ lb,
                         float* __restrict__ out, int n) {
    int t = threadIdx.x;
    int node = blockIdx.x * 32 + (t >> 3);
    if (node >= n) return;
    int tl = t & 7;
    const uint2* H8 = (const uint2*)Hm;     // row = 8 uint2 (32 halves)
    int e0 = rowptr[node], e1 = rowptr[node + 1];
    float ad_d = ad_[node];

    int  ce  = e0 + tl;
    bool vA  = ce < e1;
    int  idxA = vA ? csr[ce] : 0;
    float asA = vA ? as_[idxA] : 0.f;

    float m = -INFINITY, l = 0.f;
    float4 acc = make_float4(0.f, 0.f, 0.f, 0.f);

    for (int eb = e0; eb < e1; eb += 8) {
        uint2 u[8];
#pragma unroll
        for (int j = 0; j < 8; j++) {
            int src = __shfl(idxA, j, 8);
            u[j] = H8[(size_t)src * 8 + tl];
        }

        int  ne  = eb + 8 + tl;
        bool vB  = ne < e1;
        int  idxB = vB ? csr[ne] : 0;
        float asB = vB ? as_[idxB] : 0.f;

        float el = asA + ad_d;
        el = (el > 0.f) ? el : NEG_SLOPE * el;
        el = vA ? el : -INFINITY;

        float cm = el;
        cm = fmaxf(cm, __shfl_xor(cm, 1, 8));
        cm = fmaxf(cm, __shfl_xor(cm, 2, 8));
        cm = fmaxf(cm, __shfl_xor(cm, 4, 8));
        float m_new = fmaxf(m, cm);
        float scale = __expf(m - m_new);
        float p = vA ? __expf(el - m_new) : 0.f;

        float ps = p;
        ps += __shfl_xor(ps, 1, 8);
        ps += __shfl_xor(ps, 2, 8);
        ps += __shfl_xor(ps, 4, 8);
        l = l * scale + ps;
        acc.x *= scale; acc.y *= scale; acc.z *= scale; acc.w *= scale;
        m = m_new;

#pragma unroll
        for (int j = 0; j < 8; j++) {
            float pj  = __shfl(p, j, 8);
            float2 f01 = __half22float2(*(const __half2*)&u[j].x);
            float2 f23 = __half22float2(*(const __half2*)&u[j].y);
            acc.x += pj * f01.x; acc.y += pj * f01.y;
            acc.z += pj * f23.x; acc.w += pj * f23.y;
        }
        idxA = idxB; asA = asB; vA = vB;
    }

    float li = 1.f / (l + 1e-16f);
    float4 b4 = ((const float4*)bias)[tl];
    float4 o;
    o.x = fmaxf(acc.x * li + b4.x, 0.f);
    o.y = fmaxf(acc.y * li + b4.y, 0.f);
    o.z = fmaxf(acc.z * li + b4.z, 0.f);
    o.w = fmaxf(acc.w * li + b4.w, 0.f);

    // fused final linear: lane tl computes classes tl + 8c (c = 0..4)
    float fin0 = lb[tl];
    float fin1 = lb[tl + 8];
    float fin2 = lb[tl + 16];
    float fin3 = lb[tl + 24];
    float fin4 = lb[tl + 32];
#pragma unroll
    for (int j = 0; j < 8; j++) {
        float vx = __shfl(o.x, j, 8);
        float vy = __shfl(o.y, j, 8);
        float vz = __shfl(o.z, j, 8);
        float vw = __shfl(o.w, j, 8);
        const float* l0 = lw + (size_t)(4 * j) * 40;   // rows 4j..4j+3 of lw[32,40]
#pragma unroll
        for (int c = 0; c < 5; c++) {
            int cls = tl + 8 * c;
            float v = vx * l0[cls] + vy * l0[40 + cls] + vz * l0[80 + cls] + vw * l0[120 + cls];
            if (c == 0) fin0 += v;
            else if (c == 1) fin1 += v;
            else if (c == 2) fin2 += v;
            else if (c == 3) fin3 += v;
            else fin4 += v;
        }
    }
    float* op = out + (size_t)node * 40;
    op[tl]      = fin0;
    op[tl + 8]  = fin1;
    op[tl + 16] = fin2;
    op[tl + 24] = fin3;
    op[tl + 32] = fin4;
}

// ---------------- launch ----------------

extern "C" void kernel_launch(void* const* d_in, const int* in_sizes, int n_in,
                              void* d_out, int out_size, void* d_ws, size_t ws_size,
                              hipStream_t stream) {
    const float* x   = (const float*)d_in[0];
    const int*   ei  = (const int*)d_in[1];
    const float* W0  = (const float*)d_in[2];
    const float* as0 = (const float*)d_in[3];
    const float* ad0 = (const float*)d_in[4];
    const float* b0  = (const float*)d_in[5];
    const float* W1  = (const float*)d_in[6];
    const float* as1 = (const float*)d_in[7];
    const float* ad1 = (const float*)d_in[8];
    const float* b1  = (const float*)d_in[9];
    const float* W2  = (const float*)d_in[10];
    const float* as2 = (const float*)d_in[11];
    const float* ad2 = (const float*)d_in[12];
    const float* b2  = (const float*)d_in[13];
    const float* lw  = (const float*)d_in[14];
    const float* lb  = (const float*)d_in[15];
    float* out = (float*)d_out;

    const int n    = in_sizes[0] / 128;   // 100000 (= 32 * 3125)
    const int eraw = in_sizes[1] / 2;     // 1600000
    const int etot = eraw + n;
    const int nb   = (n + 1023) / 1024;

    char* wsp = (char*)d_ws;
    size_t off = 0;
    auto alloc = [&](size_t bytes) -> void* {
        void* p = wsp + off;
        off += (bytes + 255) & ~(size_t)255;
        return p;
    };
    __half* h16    = (__half*)alloc((size_t)n * 128 * 2);  // per-layer h table
    __half* buf16  = (__half*)alloc((size_t)n * 128 * 2);  // inter-layer activations
    __half* h2     = (__half*)alloc((size_t)n * 32 * 2);   // layer-2 h table
    __half* Wt0    = (__half*)alloc((size_t)128 * 128 * 2);
    __half* Wt1    = (__half*)alloc((size_t)128 * 128 * 2);
    float*  asb    = (float*)alloc((size_t)n * 4 * 4);
    float*  adb    = (float*)alloc((size_t)n * 4 * 4);
    int*    deg    = (int*)alloc((size_t)n * 4);
    int*    rank   = (int*)alloc((size_t)etot * 4);
    int*    rowptr = (int*)alloc((size_t)(n + 1) * 4);
    int*    csr    = (int*)alloc((size_t)etot * 4);
    int*    bsum   = (int*)alloc((size_t)nb * 4);
    int*    boffs  = (int*)alloc((size_t)nb * 4);

    // --- CSR build (single atomic pass) + W pre-transpose ---
    zero1_kernel<<<(n + 255) / 256, 256, 0, stream>>>(deg, n);
    count_rank_kernel<<<(etot + 255) / 256, 256, 0, stream>>>(ei, eraw, n, deg, rank);
    wt_f16_kernel<<<64, 256, 0, stream>>>(W0, Wt0);
    wt_f16_kernel<<<64, 256, 0, stream>>>(W1, Wt1);
    scan_local_kernel<<<nb, 1024, 0, stream>>>(deg, rowptr, bsum, n);
    scan_sums_kernel<<<1, 128, 0, stream>>>(bsum, boffs, nb);
    scan_add_kernel<<<(n + 255) / 256, 256, 0, stream>>>(rowptr, boffs, n, etot);
    scatter2_kernel<<<(etot + 255) / 256, 256, 0, stream>>>(ei, rank, eraw, n, rowptr, csr);

    // --- layer 0: 128 -> 4x32, concat ---
    gemm_mfma_f32in_kernel<<<(n + 63) / 64, 256, 0, stream>>>(x, Wt0, h16, n);
    attn_coef_f16_kernel<<<(n * 4 + 255) / 256, 256, 0, stream>>>(h16, as0, ad0, asb, adb, n);
    gat_fused_f16_kernel<<<(n + 7) / 8, 256, 0, stream>>>(h16, asb, adb, rowptr, csr, b0, buf16, n);

    // --- layer 1: 128 -> 4x32, concat ---
    gemm_mfma_f16in_kernel<<<(n + 63) / 64, 256, 0, stream>>>(buf16, Wt1, h16, n);
    attn_coef_f16_kernel<<<(n * 4 + 255) / 256, 256, 0, stream>>>(h16, as1, ad1, asb, adb, n);
    gat_fused_f16_kernel<<<(n + 7) / 8, 256, 0, stream>>>(h16, asb, adb, rowptr, csr, b1, buf16, n);

    // --- layer 2: 128 -> 1x32, + fused final linear ---
    gemm_l2_f16_kernel<<<(n + 7) / 8, 128, 0, stream>>>(buf16, W2, h2, n);
    attn_coef_l2_f16_kernel<<<(n + 255) / 256, 256, 0, stream>>>(h2, as2, ad2, asb, adb, n);
    gat_fused_l2_kernel<<<(n + 31) / 32, 256, 0, stream>>>(h2, asb, adb, rowptr, csr, b2, lw, lb, out, n);
}

// Round 7
// 501.053 us; speedup vs baseline: 1.4055x; 1.0554x over previous
//
#include <hip/hip_runtime.h>
#include <hip/hip_bf16.h>
#include <hip/hip_fp16.h>
#include <math.h>

// ---------------------------------------------------------------------------
// GAT (3 layers, heads=4/4/1, hid=32) + final linear.
// R18: MFMA GEMM overhaul. R17's B-loads were 16-segment fragmented
//      (lane l15 -> row stride 256 B): ~512 L1 transactions/wave vs 160 cyc
//      MFMA -> TA-bound. Now: W pre-packed in fragment order (B-loads are
//      64x16B contiguous), 2 row-tiles per wave (64 MFMA per 8 B-loads),
//      attn-coef fused into the GEMM epilogue (shfl_xor width-16 reduction)
//      killing two 25.6MB-read kernels. Fused gather kernels unchanged
//      (at the ~4 TB/s L2-miss/L3 random wall).
// ---------------------------------------------------------------------------

#define NEG_SLOPE 0.2f

typedef __attribute__((ext_vector_type(8))) _Float16 f16x8;
typedef __attribute__((ext_vector_type(4))) float    f32x4;

// ---------------- CSR build ----------------

__global__ void zero1_kernel(int* __restrict__ a, int n) {
    int i = blockIdx.x * blockDim.x + threadIdx.x;
    if (i < n) a[i] = 0;
}

__global__ void count_rank_kernel(const int* __restrict__ ei, int eraw, int n,
                                  int* __restrict__ deg, int* __restrict__ rank) {
    int i = blockIdx.x * blockDim.x + threadIdx.x;
    int etot = eraw + n;
    if (i >= etot) return;
    int dst = (i < eraw) ? ei[eraw + i] : (i - eraw);
    rank[i] = atomicAdd(&deg[dst], 1);
}

__global__ __launch_bounds__(1024)
void scan_local_kernel(const int* __restrict__ deg, int* __restrict__ rowptr,
                       int* __restrict__ bsum, int n) {
    __shared__ int buf[1024];
    int tid = threadIdx.x;
    int i = blockIdx.x * 1024 + tid;
    int v = (i < n) ? deg[i] : 0;
    buf[tid] = v;
    __syncthreads();
    for (int off = 1; off < 1024; off <<= 1) {
        int t = (tid >= off) ? buf[tid - off] : 0;
        __syncthreads();
        buf[tid] += t;
        __syncthreads();
    }
    if (i < n) rowptr[i] = buf[tid] - v;
    if (tid == 1023) bsum[blockIdx.x] = buf[1023];
}

__global__ __launch_bounds__(128)
void scan_sums_kernel(const int* __restrict__ bsum, int* __restrict__ boffs, int nb) {
    __shared__ int buf[128];
    int tid = threadIdx.x;
    int v = (tid < nb) ? bsum[tid] : 0;
    buf[tid] = v;
    __syncthreads();
    for (int off = 1; off < 128; off <<= 1) {
        int t = (tid >= off) ? buf[tid - off] : 0;
        __syncthreads();
        buf[tid] += t;
        __syncthreads();
    }
    if (tid < nb) boffs[tid] = buf[tid] - v;
}

__global__ void scan_add_kernel(int* __restrict__ rowptr, const int* __restrict__ boffs,
                                int n, int etot) {
    int i = blockIdx.x * blockDim.x + threadIdx.x;
    if (i < n) rowptr[i] += boffs[i >> 10];
    if (i == 0) rowptr[n] = etot;
}

__global__ void scatter2_kernel(const int* __restrict__ ei, const int* __restrict__ rank,
                                int eraw, int n, const int* __restrict__ rowptr,
                                int* __restrict__ csr_src) {
    int i = blockIdx.x * blockDim.x + threadIdx.x;
    int etot = eraw + n;
    if (i >= etot) return;
    int src, dst;
    if (i < eraw) { src = ei[i]; dst = ei[eraw + i]; }
    else          { src = i - eraw; dst = src; }
    csr_src[rowptr[dst] + rank[i]] = src;
}

// ---------------- W -> fp16 packed in MFMA B-fragment order ----------------
// Wpack[((ct*4+ks)*64 + lane)*8 + j] = W[(ks*32 + (lane>>4)*8 + j)*128 + ct*16 + (lane&15)]

__global__ void wpack_f16_kernel(const float* __restrict__ W, __half* __restrict__ Wp) {
    int i = blockIdx.x * blockDim.x + threadIdx.x;   // 16384
    int j    = i & 7;
    int lane = (i >> 3) & 63;
    int ks   = (i >> 9) & 3;
    int ct   = i >> 11;
    int k = ks * 32 + (lane >> 4) * 8 + j;
    int c = ct * 16 + (lane & 15);
    Wp[i] = __float2half(W[k * 128 + c]);
}

// ---------------- MFMA GEMM + fused attn-coef ------------------------------
// Block = 256 threads = 4 waves. Wave handles 32 rows (2 row-tiles of 16).
// Per wave: 8 col-tiles, K=128 in 4 steps -> 64 MFMAs, 8 coalesced B-loads.
// Epilogue: H store (fp16) + as/ad via width-16 shfl_xor reduction.

template <bool F32IN>
__global__ __launch_bounds__(256)
void gemm_mfma_coef_kernel(const void* __restrict__ Xv, const __half* __restrict__ Wp,
                           const float* __restrict__ a_s, const float* __restrict__ a_d,
                           __half* __restrict__ H, float* __restrict__ as_out,
                           float* __restrict__ ad_out, int n) {
    int t = threadIdx.x;
    int wave = t >> 6, lane = t & 63;
    int l15 = lane & 15;
    int kg  = lane >> 4;                 // 0..3
    int base = blockIdx.x * 128 + wave * 32;

    int row0 = base + l15;
    int row1 = base + 16 + l15;
    int r0c = (row0 < n) ? row0 : 0;
    int r1c = (row1 < n) ? row1 : 0;

    f32x4 acc[2][8];
#pragma unroll
    for (int tt = 0; tt < 2; tt++)
#pragma unroll
        for (int i = 0; i < 8; i++) acc[tt][i] = (f32x4){0.f, 0.f, 0.f, 0.f};

#pragma unroll
    for (int ks = 0; ks < 4; ks++) {
        f16x8 a0, a1;
        if constexpr (F32IN) {
            const float* X = (const float*)Xv;
            const float* p0 = X + (size_t)r0c * 128 + kg * 8 + ks * 32;
            const float* p1 = X + (size_t)r1c * 128 + kg * 8 + ks * 32;
            float4 x0 = *(const float4*)(p0), x1 = *(const float4*)(p0 + 4);
            a0[0] = (_Float16)x0.x; a0[1] = (_Float16)x0.y; a0[2] = (_Float16)x0.z; a0[3] = (_Float16)x0.w;
            a0[4] = (_Float16)x1.x; a0[5] = (_Float16)x1.y; a0[6] = (_Float16)x1.z; a0[7] = (_Float16)x1.w;
            float4 y0 = *(const float4*)(p1), y1 = *(const float4*)(p1 + 4);
            a1[0] = (_Float16)y0.x; a1[1] = (_Float16)y0.y; a1[2] = (_Float16)y0.z; a1[3] = (_Float16)y0.w;
            a1[4] = (_Float16)y1.x; a1[5] = (_Float16)y1.y; a1[6] = (_Float16)y1.z; a1[7] = (_Float16)y1.w;
        } else {
            const __half* X = (const __half*)Xv;
            a0 = *(const f16x8*)(X + (size_t)r0c * 128 + kg * 8 + ks * 32);
            a1 = *(const f16x8*)(X + (size_t)r1c * 128 + kg * 8 + ks * 32);
        }
#pragma unroll
        for (int ct = 0; ct < 8; ct++) {
            f16x8 b = *(const f16x8*)(Wp + (size_t)((ct * 4 + ks) * 64 + lane) * 8);
            acc[0][ct] = __builtin_amdgcn_mfma_f32_16x16x32_f16(a0, b, acc[0][ct], 0, 0, 0);
            acc[1][ct] = __builtin_amdgcn_mfma_f32_16x16x32_f16(a1, b, acc[1][ct], 0, 0, 0);
        }
    }

    // H store: D layout col = l15, row = kg*4 + r (within 16-row tile)
#pragma unroll
    for (int tt = 0; tt < 2; tt++) {
#pragma unroll
        for (int ct = 0; ct < 8; ct++) {
#pragma unroll
            for (int r = 0; r < 4; r++) {
                int orow = base + tt * 16 + kg * 4 + r;
                if (orow < n)
                    H[(size_t)orow * 128 + ct * 16 + l15] = __float2half(acc[tt][ct][r]);
            }
        }
    }

    // fused attn-coef: as/ad per (row, head); row's 128 cols live in the
    // 16 lanes of this kg-group (l15 = col&15, ct = col>>4).
#pragma unroll
    for (int h = 0; h < 4; h++) {
        float ws0 = a_s[h * 32 + l15];
        float ws1 = a_s[h * 32 + 16 + l15];
        float wd0 = a_d[h * 32 + l15];
        float wd1 = a_d[h * 32 + 16 + l15];
#pragma unroll
        for (int tt = 0; tt < 2; tt++) {
#pragma unroll
            for (int r = 0; r < 4; r++) {
                float v0 = acc[tt][2 * h][r];
                float v1 = acc[tt][2 * h + 1][r];
                float ps = v0 * ws0 + v1 * ws1;
                float pd = v0 * wd0 + v1 * wd1;
                ps += __shfl_xor(ps, 1, 16); pd += __shfl_xor(pd, 1, 16);
                ps += __shfl_xor(ps, 2, 16); pd += __shfl_xor(pd, 2, 16);
                ps += __shfl_xor(ps, 4, 16); pd += __shfl_xor(pd, 4, 16);
                ps += __shfl_xor(ps, 8, 16); pd += __shfl_xor(pd, 8, 16);
                int orow = base + tt * 16 + kg * 4 + r;
                if (l15 == 0 && orow < n) {
                    as_out[(size_t)orow * 4 + h] = ps;
                    ad_out[(size_t)orow * 4 + h] = pd;
                }
            }
        }
    }
}

// ---------------- layer-2 GEMM: [n,128] fp16 @ [128,32] -> [n,32] fp16 -----

__global__ __launch_bounds__(128)
void gemm_l2_f16_kernel(const __half* __restrict__ X, const float* __restrict__ W,
                        __half* __restrict__ H, int n) {
    __shared__ float xs[8][129];
    int base = blockIdx.x * 8;
    int tid = threadIdx.x;
#pragma unroll
    for (int it = 0; it < 4; it++) {
        int i = tid + it * 128;          // 0..511 half2 elements
        int r = i >> 6, c2 = i & 63;
        int row = base + r;
        __half2 v = (row < n) ? ((const __half2*)(X + (size_t)row * 128))[c2]
                              : __floats2half2_rn(0.f, 0.f);
        float2 f = __half22float2(v);
        xs[r][c2 * 2] = f.x; xs[r][c2 * 2 + 1] = f.y;
    }
    __syncthreads();
    int col  = tid & 31;
    int rsub = tid >> 5;                 // 0..3
    float acc0 = 0.f, acc1 = 0.f;
    for (int k = 0; k < 128; k++) {
        float w = W[k * 32 + col];
        acc0 += xs[rsub][k] * w;
        acc1 += xs[rsub + 4][k] * w;
    }
    int row0 = base + rsub;
    if (row0 < n)     H[(size_t)row0 * 32 + col]       = __float2half(acc0);
    if (row0 + 4 < n) H[(size_t)(row0 + 4) * 32 + col] = __float2half(acc1);
}

// layer-2 attn coef: 1 head, 32 channels, fp16 H
__global__ void attn_coef_l2_f16_kernel(const __half* __restrict__ H,
                                        const float* __restrict__ a_s,
                                        const float* __restrict__ a_d,
                                        float* __restrict__ as_out,
                                        float* __restrict__ ad_out, int n) {
    int i = blockIdx.x * blockDim.x + threadIdx.x;
    if (i >= n) return;
    const __half2* hp = (const __half2*)(H + (size_t)i * 32);
    float s = 0.f, d = 0.f;
#pragma unroll
    for (int c2 = 0; c2 < 16; c2++) {
        float2 v = __half22float2(hp[c2]);
        s += v.x * a_s[2 * c2] + v.y * a_s[2 * c2 + 1];
        d += v.x * a_d[2 * c2] + v.y * a_d[2 * c2 + 1];
    }
    as_out[i] = s;
    ad_out[i] = d;
}

// ---------------- fused online-softmax aggregation, fp16 gathers -----------

struct h4pack { __half2 a, b; };   // 4 halves = 8 B

__global__ __launch_bounds__(256)
void gat_fused_f16_kernel(const __half* __restrict__ Hm,
                          const float* __restrict__ as_,
                          const float* __restrict__ ad_,
                          const int* __restrict__ rowptr,
                          const int* __restrict__ csr,
                          const float* __restrict__ bias,
                          __half* __restrict__ out, int n) {
    constexpr int GS = 32;
    int t = threadIdx.x;
    int node = blockIdx.x * 8 + (t >> 5);
    if (node >= n) return;
    int tl = t & 31;
    int h  = tl >> 3;
    int k8 = tl & 7;
    const uint2* H8 = (const uint2*)Hm;     // 8 B = 4 halves per lane
    int e0 = rowptr[node], e1 = rowptr[node + 1];
    float ad_d = ad_[(size_t)node * 4 + h];

    int  ce  = e0 + k8;
    bool vA  = ce < e1;
    int  idxA = vA ? csr[ce] : 0;
    float asA = vA ? as_[(size_t)idxA * 4 + h] : 0.f;

    float m = -INFINITY, l = 0.f;
    float4 acc = make_float4(0.f, 0.f, 0.f, 0.f);

    for (int eb = e0; eb < e1; eb += 8) {
        uint2 u[8];
#pragma unroll
        for (int j = 0; j < 8; j++) {
            int src = __shfl(idxA, j, 8);
            u[j] = H8[(size_t)src * GS + tl];
        }

        int  ne  = eb + 8 + k8;
        bool vB  = ne < e1;
        int  idxB = vB ? csr[ne] : 0;
        float asB = vB ? as_[(size_t)idxB * 4 + h] : 0.f;

        float el = asA + ad_d;
        el = (el > 0.f) ? el : NEG_SLOPE * el;
        el = vA ? el : -INFINITY;

        float cm = el;
        cm = fmaxf(cm, __shfl_xor(cm, 1, 8));
        cm = fmaxf(cm, __shfl_xor(cm, 2, 8));
        cm = fmaxf(cm, __shfl_xor(cm, 4, 8));
        float m_new = fmaxf(m, cm);
        float scale = __expf(m - m_new);
        float p = vA ? __expf(el - m_new) : 0.f;

        float ps = p;
        ps += __shfl_xor(ps, 1, 8);
        ps += __shfl_xor(ps, 2, 8);
        ps += __shfl_xor(ps, 4, 8);
        l = l * scale + ps;
        acc.x *= scale; acc.y *= scale; acc.z *= scale; acc.w *= scale;
        m = m_new;

#pragma unroll
        for (int j = 0; j < 8; j++) {
            float pj  = __shfl(p, j, 8);
            float2 f01 = __half22float2(*(const __half2*)&u[j].x);
            float2 f23 = __half22float2(*(const __half2*)&u[j].y);
            acc.x += pj * f01.x; acc.y += pj * f01.y;
            acc.z += pj * f23.x; acc.w += pj * f23.y;
        }
        idxA = idxB; asA = asB; vA = vB;
    }

    float li = 1.f / (l + 1e-16f);
    float4 b4 = ((const float4*)bias)[tl];
    float4 o;
    o.x = fmaxf(acc.x * li + b4.x, 0.f);
    o.y = fmaxf(acc.y * li + b4.y, 0.f);
    o.z = fmaxf(acc.z * li + b4.z, 0.f);
    o.w = fmaxf(acc.w * li + b4.w, 0.f);
    h4pack po;
    po.a = __floats2half2_rn(o.x, o.y);
    po.b = __floats2half2_rn(o.z, o.w);
    ((h4pack*)out)[(size_t)node * 32 + tl] = po;
}

// ---------------- layer-2 fused: fp16 gathers + bias/relu + final linear ---

__global__ __launch_bounds__(256)
void gat_fused_l2_kernel(const __half* __restrict__ Hm,
                         const float* __restrict__ as_,
                         const float* __restrict__ ad_,
                         const int* __restrict__ rowptr,
                         const int* __restrict__ csr,
                         const float* __restrict__ bias,
                         const float* __restrict__ lw,
                         const float* __restrict__ lb,
                         float* __restrict__ out, int n) {
    int t = threadIdx.x;
    int node = blockIdx.x * 32 + (t >> 3);
    if (node >= n) return;
    int tl = t & 7;
    const uint2* H8 = (const uint2*)Hm;     // row = 8 uint2 (32 halves)
    int e0 = rowptr[node], e1 = rowptr[node + 1];
    float ad_d = ad_[node];

    int  ce  = e0 + tl;
    bool vA  = ce < e1;
    int  idxA = vA ? csr[ce] : 0;
    float asA = vA ? as_[idxA] : 0.f;

    float m = -INFINITY, l = 0.f;
    float4 acc = make_float4(0.f, 0.f, 0.f, 0.f);

    for (int eb = e0; eb < e1; eb += 8) {
        uint2 u[8];
#pragma unroll
        for (int j = 0; j < 8; j++) {
            int src = __shfl(idxA, j, 8);
            u[j] = H8[(size_t)src * 8 + tl];
        }

        int  ne  = eb + 8 + tl;
        bool vB  = ne < e1;
        int  idxB = vB ? csr[ne] : 0;
        float asB = vB ? as_[idxB] : 0.f;

        float el = asA + ad_d;
        el = (el > 0.f) ? el : NEG_SLOPE * el;
        el = vA ? el : -INFINITY;

        float cm = el;
        cm = fmaxf(cm, __shfl_xor(cm, 1, 8));
        cm = fmaxf(cm, __shfl_xor(cm, 2, 8));
        cm = fmaxf(cm, __shfl_xor(cm, 4, 8));
        float m_new = fmaxf(m, cm);
        float scale = __expf(m - m_new);
        float p = vA ? __expf(el - m_new) : 0.f;

        float ps = p;
        ps += __shfl_xor(ps, 1, 8);
        ps += __shfl_xor(ps, 2, 8);
        ps += __shfl_xor(ps, 4, 8);
        l = l * scale + ps;
        acc.x *= scale; acc.y *= scale; acc.z *= scale; acc.w *= scale;
        m = m_new;

#pragma unroll
        for (int j = 0; j < 8; j++) {
            float pj  = __shfl(p, j, 8);
            float2 f01 = __half22float2(*(const __half2*)&u[j].x);
            float2 f23 = __half22float2(*(const __half2*)&u[j].y);
            acc.x += pj * f01.x; acc.y += pj * f01.y;
            acc.z += pj * f23.x; acc.w += pj * f23.y;
        }
        idxA = idxB; asA = asB; vA = vB;
    }

    float li = 1.f / (l + 1e-16f);
    float4 b4 = ((const float4*)bias)[tl];
    float4 o;
    o.x = fmaxf(acc.x * li + b4.x, 0.f);
    o.y = fmaxf(acc.y * li + b4.y, 0.f);
    o.z = fmaxf(acc.z * li + b4.z, 0.f);
    o.w = fmaxf(acc.w * li + b4.w, 0.f);

    // fused final linear: lane tl computes classes tl + 8c (c = 0..4)
    float fin0 = lb[tl];
    float fin1 = lb[tl + 8];
    float fin2 = lb[tl + 16];
    float fin3 = lb[tl + 24];
    float fin4 = lb[tl + 32];
#pragma unroll
    for (int j = 0; j < 8; j++) {
        float vx = __shfl(o.x, j, 8);
        float vy = __shfl(o.y, j, 8);
        float vz = __shfl(o.z, j, 8);
        float vw = __shfl(o.w, j, 8);
        const float* l0 = lw + (size_t)(4 * j) * 40;   // rows 4j..4j+3 of lw[32,40]
#pragma unroll
        for (int c = 0; c < 5; c++) {
            int cls = tl + 8 * c;
            float v = vx * l0[cls] + vy * l0[40 + cls] + vz * l0[80 + cls] + vw * l0[120 + cls];
            if (c == 0) fin0 += v;
            else if (c == 1) fin1 += v;
            else if (c == 2) fin2 += v;
            else if (c == 3) fin3 += v;
            else fin4 += v;
        }
    }
    float* op = out + (size_t)node * 40;
    op[tl]      = fin0;
    op[tl + 8]  = fin1;
    op[tl + 16] = fin2;
    op[tl + 24] = fin3;
    op[tl + 32] = fin4;
}

// ---------------- launch ----------------

extern "C" void kernel_launch(void* const* d_in, const int* in_sizes, int n_in,
                              void* d_out, int out_size, void* d_ws, size_t ws_size,
                              hipStream_t stream) {
    const float* x   = (const float*)d_in[0];
    const int*   ei  = (const int*)d_in[1];
    const float* W0  = (const float*)d_in[2];
    const float* as0 = (const float*)d_in[3];
    const float* ad0 = (const float*)d_in[4];
    const float* b0  = (const float*)d_in[5];
    const float* W1  = (const float*)d_in[6];
    const float* as1 = (const float*)d_in[7];
    const float* ad1 = (const float*)d_in[8];
    const float* b1  = (const float*)d_in[9];
    const float* W2  = (const float*)d_in[10];
    const float* as2 = (const float*)d_in[11];
    const float* ad2 = (const float*)d_in[12];
    const float* b2  = (const float*)d_in[13];
    const float* lw  = (const float*)d_in[14];
    const float* lb  = (const float*)d_in[15];
    float* out = (float*)d_out;

    const int n    = in_sizes[0] / 128;   // 100000 (= 32 * 3125)
    const int eraw = in_sizes[1] / 2;     // 1600000
    const int etot = eraw + n;
    const int nb   = (n + 1023) / 1024;

    char* wsp = (char*)d_ws;
    size_t off = 0;
    auto alloc = [&](size_t bytes) -> void* {
        void* p = wsp + off;
        off += (bytes + 255) & ~(size_t)255;
        return p;
    };
    __half* h16    = (__half*)alloc((size_t)n * 128 * 2);  // per-layer h table
    __half* buf16  = (__half*)alloc((size_t)n * 128 * 2);  // inter-layer activations
    __half* h2     = (__half*)alloc((size_t)n * 32 * 2);   // layer-2 h table
    __half* Wp0    = (__half*)alloc((size_t)128 * 128 * 2);
    __half* Wp1    = (__half*)alloc((size_t)128 * 128 * 2);
    float*  asb    = (float*)alloc((size_t)n * 4 * 4);
    float*  adb    = (float*)alloc((size_t)n * 4 * 4);
    int*    deg    = (int*)alloc((size_t)n * 4);
    int*    rank   = (int*)alloc((size_t)etot * 4);
    int*    rowptr = (int*)alloc((size_t)(n + 1) * 4);
    int*    csr    = (int*)alloc((size_t)etot * 4);
    int*    bsum   = (int*)alloc((size_t)nb * 4);
    int*    boffs  = (int*)alloc((size_t)nb * 4);

    // --- CSR build (single atomic pass) + W pre-pack ---
    zero1_kernel<<<(n + 255) / 256, 256, 0, stream>>>(deg, n);
    count_rank_kernel<<<(etot + 255) / 256, 256, 0, stream>>>(ei, eraw, n, deg, rank);
    wpack_f16_kernel<<<64, 256, 0, stream>>>(W0, Wp0);
    wpack_f16_kernel<<<64, 256, 0, stream>>>(W1, Wp1);
    scan_local_kernel<<<nb, 1024, 0, stream>>>(deg, rowptr, bsum, n);
    scan_sums_kernel<<<1, 128, 0, stream>>>(bsum, boffs, nb);
    scan_add_kernel<<<(n + 255) / 256, 256, 0, stream>>>(rowptr, boffs, n, etot);
    scatter2_kernel<<<(etot + 255) / 256, 256, 0, stream>>>(ei, rank, eraw, n, rowptr, csr);

    const int gblocks = (n + 127) / 128;

    // --- layer 0: 128 -> 4x32, concat ---
    gemm_mfma_coef_kernel<true><<<gblocks, 256, 0, stream>>>(x, Wp0, as0, ad0, h16, asb, adb, n);
    gat_fused_f16_kernel<<<(n + 7) / 8, 256, 0, stream>>>(h16, asb, adb, rowptr, csr, b0, buf16, n);

    // --- layer 1: 128 -> 4x32, concat ---
    gemm_mfma_coef_kernel<false><<<gblocks, 256, 0, stream>>>(buf16, Wp1, as1, ad1, h16, asb, adb, n);
    gat_fused_f16_kernel<<<(n + 7) / 8, 256, 0, stream>>>(h16, asb, adb, rowptr, csr, b1, buf16, n);

    // --- layer 2: 128 -> 1x32, + fused final linear ---
    gemm_l2_f16_kernel<<<(n + 7) / 8, 128, 0, stream>>>(buf16, W2, h2, n);
    attn_coef_l2_f16_kernel<<<(n + 255) / 256, 256, 0, stream>>>(h2, as2, ad2, asb, adb, n);
    gat_fused_l2_kernel<<<(n + 31) / 32, 256, 0, stream>>>(h2, asb, adb, rowptr, csr, b2, lw, lb, out, n);
}

// Round 9
// 466.734 us; speedup vs baseline: 1.5088x; 1.0735x over previous
//
#include <hip/hip_runtime.h>
#include <hip/hip_bf16.h>
#include <hip/hip_fp16.h>
#include <math.h>

// ---------------------------------------------------------------------------
// GAT (3 layers, heads=4/4/1, hid=32) + final linear.
// R20: fixes R19's correctness bug - epilogue copy used uint2 (8 B = 4
//      halves) while striding 8 halves, leaving half of every H row stale
//      (absmax 0.37). Now uint4 (16 B = 8 halves); LDS rows padded for 16-B
//      alignment (136 halves for the 128-col tile, 40 for the 32-col tile).
//      Structure otherwise identical to R19: MFMA GEMMs with LDS-staged
//      coalesced epilogue + fused shuffle-free attn-coef; layer-2 GEMM
//      MFMA-ized with fused coef; fused gather kernels untouched.
// ---------------------------------------------------------------------------

#define NEG_SLOPE 0.2f

typedef __attribute__((ext_vector_type(8))) _Float16 f16x8;
typedef __attribute__((ext_vector_type(4))) float    f32x4;

// ---------------- CSR build ----------------

__global__ void zero1_kernel(int* __restrict__ a, int n) {
    int i = blockIdx.x * blockDim.x + threadIdx.x;
    if (i < n) a[i] = 0;
}

__global__ void count_rank_kernel(const int* __restrict__ ei, int eraw, int n,
                                  int* __restrict__ deg, int* __restrict__ rank) {
    int i = blockIdx.x * blockDim.x + threadIdx.x;
    int etot = eraw + n;
    if (i >= etot) return;
    int dst = (i < eraw) ? ei[eraw + i] : (i - eraw);
    rank[i] = atomicAdd(&deg[dst], 1);
}

__global__ __launch_bounds__(1024)
void scan_local_kernel(const int* __restrict__ deg, int* __restrict__ rowptr,
                       int* __restrict__ bsum, int n) {
    __shared__ int buf[1024];
    int tid = threadIdx.x;
    int i = blockIdx.x * 1024 + tid;
    int v = (i < n) ? deg[i] : 0;
    buf[tid] = v;
    __syncthreads();
    for (int off = 1; off < 1024; off <<= 1) {
        int t = (tid >= off) ? buf[tid - off] : 0;
        __syncthreads();
        buf[tid] += t;
        __syncthreads();
    }
    if (i < n) rowptr[i] = buf[tid] - v;
    if (tid == 1023) bsum[blockIdx.x] = buf[1023];
}

__global__ __launch_bounds__(128)
void scan_sums_kernel(const int* __restrict__ bsum, int* __restrict__ boffs, int nb) {
    __shared__ int buf[128];
    int tid = threadIdx.x;
    int v = (tid < nb) ? bsum[tid] : 0;
    buf[tid] = v;
    __syncthreads();
    for (int off = 1; off < 128; off <<= 1) {
        int t = (tid >= off) ? buf[tid - off] : 0;
        __syncthreads();
        buf[tid] += t;
        __syncthreads();
    }
    if (tid < nb) boffs[tid] = buf[tid] - v;
}

__global__ void scan_add_kernel(int* __restrict__ rowptr, const int* __restrict__ boffs,
                                int n, int etot) {
    int i = blockIdx.x * blockDim.x + threadIdx.x;
    if (i < n) rowptr[i] += boffs[i >> 10];
    if (i == 0) rowptr[n] = etot;
}

__global__ void scatter2_kernel(const int* __restrict__ ei, const int* __restrict__ rank,
                                int eraw, int n, const int* __restrict__ rowptr,
                                int* __restrict__ csr_src) {
    int i = blockIdx.x * blockDim.x + threadIdx.x;
    int etot = eraw + n;
    if (i >= etot) return;
    int src, dst;
    if (i < eraw) { src = ei[i]; dst = ei[eraw + i]; }
    else          { src = i - eraw; dst = src; }
    csr_src[rowptr[dst] + rank[i]] = src;
}

// ---------------- W -> fp16 packed in MFMA B-fragment order ----------------
// OUTC = output cols (128 or 32). Wp[((ct*4+ks)*64+lane)*8+j] =
//   W[(ks*32 + (lane>>4)*8 + j)*OUTC + ct*16 + (lane&15)]

template <int OUTC>
__global__ void wpack_f16_kernel(const float* __restrict__ W, __half* __restrict__ Wp) {
    int i = blockIdx.x * blockDim.x + threadIdx.x;   // 128*OUTC
    int j    = i & 7;
    int lane = (i >> 3) & 63;
    int ks   = (i >> 9) & 3;
    int ct   = i >> 11;
    int k = ks * 32 + (lane >> 4) * 8 + j;
    int c = ct * 16 + (lane & 15);
    Wp[i] = __float2half(W[k * OUTC + c]);
}

// ---------------- MFMA GEMM + fused attn-coef (layers 0/1) -----------------
// Block = 256 threads = 4 waves. Wave handles 32 rows (2 row-tiles of 16),
// 8 col-tiles, K=128 in 4 steps -> 64 MFMA per wave.
// Epilogue via LDS: coalesced uint4 H store + shuffle-free as/ad.

template <bool F32IN>
__global__ __launch_bounds__(256)
void gemm_mfma_coef_kernel(const void* __restrict__ Xv, const __half* __restrict__ Wp,
                           const float* __restrict__ a_s, const float* __restrict__ a_d,
                           __half* __restrict__ H, float* __restrict__ as_out,
                           float* __restrict__ ad_out, int n) {
    __shared__ __half hs[4][32][136];   // 34,816 B; 272 B/row: 16B-aligned
    int t = threadIdx.x;
    int wave = t >> 6, lane = t & 63;
    int l15 = lane & 15;
    int kg  = lane >> 4;                 // 0..3
    int wbase = blockIdx.x * 128 + wave * 32;

    int row0 = wbase + l15;
    int row1 = wbase + 16 + l15;
    int r0c = (row0 < n) ? row0 : 0;
    int r1c = (row1 < n) ? row1 : 0;

    f32x4 acc[2][8];
#pragma unroll
    for (int tt = 0; tt < 2; tt++)
#pragma unroll
        for (int i = 0; i < 8; i++) acc[tt][i] = (f32x4){0.f, 0.f, 0.f, 0.f};

#pragma unroll
    for (int ks = 0; ks < 4; ks++) {
        f16x8 a0, a1;
        if constexpr (F32IN) {
            const float* X = (const float*)Xv;
            const float* p0 = X + (size_t)r0c * 128 + kg * 8 + ks * 32;
            const float* p1 = X + (size_t)r1c * 128 + kg * 8 + ks * 32;
            float4 x0 = *(const float4*)(p0), x1 = *(const float4*)(p0 + 4);
            a0[0] = (_Float16)x0.x; a0[1] = (_Float16)x0.y; a0[2] = (_Float16)x0.z; a0[3] = (_Float16)x0.w;
            a0[4] = (_Float16)x1.x; a0[5] = (_Float16)x1.y; a0[6] = (_Float16)x1.z; a0[7] = (_Float16)x1.w;
            float4 y0 = *(const float4*)(p1), y1 = *(const float4*)(p1 + 4);
            a1[0] = (_Float16)y0.x; a1[1] = (_Float16)y0.y; a1[2] = (_Float16)y0.z; a1[3] = (_Float16)y0.w;
            a1[4] = (_Float16)y1.x; a1[5] = (_Float16)y1.y; a1[6] = (_Float16)y1.z; a1[7] = (_Float16)y1.w;
        } else {
            const __half* X = (const __half*)Xv;
            a0 = *(const f16x8*)(X + (size_t)r0c * 128 + kg * 8 + ks * 32);
            a1 = *(const f16x8*)(X + (size_t)r1c * 128 + kg * 8 + ks * 32);
        }
#pragma unroll
        for (int ct = 0; ct < 8; ct++) {
            f16x8 b = *(const f16x8*)(Wp + (size_t)((ct * 4 + ks) * 64 + lane) * 8);
            acc[0][ct] = __builtin_amdgcn_mfma_f32_16x16x32_f16(a0, b, acc[0][ct], 0, 0, 0);
            acc[1][ct] = __builtin_amdgcn_mfma_f32_16x16x32_f16(a1, b, acc[1][ct], 0, 0, 0);
        }
    }

    // stage to LDS (D layout: row = tt*16 + kg*4 + r, col = ct*16 + l15)
#pragma unroll
    for (int tt = 0; tt < 2; tt++)
#pragma unroll
        for (int ct = 0; ct < 8; ct++)
#pragma unroll
            for (int r = 0; r < 4; r++)
                hs[wave][tt * 16 + kg * 4 + r][ct * 16 + l15] = __float2half(acc[tt][ct][r]);
    __syncthreads();

    // coalesced H store: 8 iters x (4 rows x 256 B contiguous), 16 B/lane
#pragma unroll
    for (int it = 0; it < 8; it++) {
        int lr    = it * 4 + (lane >> 4);      // 0..31
        int chunk = lane & 15;                 // 16B chunk within 256B row
        int orow  = wbase + lr;
        if (orow < n) {
            uint4 v = *(const uint4*)&hs[wave][lr][chunk * 8];
            *(uint4*)(H + (size_t)orow * 128 + chunk * 8) = v;
        }
    }

    // shuffle-free attn-coef: lane owns (row = lane&31, heads hh, hh+2)
    {
        int row = lane & 31;
        int hh  = lane >> 5;                   // 0 or 1
        int orow = wbase + row;
        if (orow < n) {
#pragma unroll
            for (int hi = 0; hi < 2; hi++) {
                int h = hh + 2 * hi;
                const __half2* hp = (const __half2*)&hs[wave][row][h * 32];
                float s = 0.f, d = 0.f;
#pragma unroll
                for (int c2 = 0; c2 < 16; c2++) {
                    float2 v = __half22float2(hp[c2]);
                    s += v.x * a_s[h * 32 + 2 * c2] + v.y * a_s[h * 32 + 2 * c2 + 1];
                    d += v.x * a_d[h * 32 + 2 * c2] + v.y * a_d[h * 32 + 2 * c2 + 1];
                }
                as_out[(size_t)orow * 4 + h] = s;
                ad_out[(size_t)orow * 4 + h] = d;
            }
        }
    }
}

// ---------------- layer-2 MFMA GEMM + fused coef ---------------------------
// [n,128] fp16 @ [128,32] -> [n,32] fp16. Wave = 32 rows, 2 col-tiles,
// 16 MFMA. Fused 1-head coef in epilogue.

__global__ __launch_bounds__(256)
void gemm_mfma_l2_kernel(const __half* __restrict__ X, const __half* __restrict__ Wp,
                         const float* __restrict__ a_s, const float* __restrict__ a_d,
                         __half* __restrict__ H, float* __restrict__ as_out,
                         float* __restrict__ ad_out, int n) {
    __shared__ __half hs[4][32][40];    // 10,240 B; 80 B/row: 16B-aligned
    int t = threadIdx.x;
    int wave = t >> 6, lane = t & 63;
    int l15 = lane & 15;
    int kg  = lane >> 4;
    int wbase = blockIdx.x * 128 + wave * 32;

    int row0 = wbase + l15;
    int row1 = wbase + 16 + l15;
    int r0c = (row0 < n) ? row0 : 0;
    int r1c = (row1 < n) ? row1 : 0;

    f32x4 acc[2][2];
#pragma unroll
    for (int tt = 0; tt < 2; tt++)
#pragma unroll
        for (int i = 0; i < 2; i++) acc[tt][i] = (f32x4){0.f, 0.f, 0.f, 0.f};

#pragma unroll
    for (int ks = 0; ks < 4; ks++) {
        f16x8 a0 = *(const f16x8*)(X + (size_t)r0c * 128 + kg * 8 + ks * 32);
        f16x8 a1 = *(const f16x8*)(X + (size_t)r1c * 128 + kg * 8 + ks * 32);
#pragma unroll
        for (int ct = 0; ct < 2; ct++) {
            f16x8 b = *(const f16x8*)(Wp + (size_t)((ct * 4 + ks) * 64 + lane) * 8);
            acc[0][ct] = __builtin_amdgcn_mfma_f32_16x16x32_f16(a0, b, acc[0][ct], 0, 0, 0);
            acc[1][ct] = __builtin_amdgcn_mfma_f32_16x16x32_f16(a1, b, acc[1][ct], 0, 0, 0);
        }
    }

#pragma unroll
    for (int tt = 0; tt < 2; tt++)
#pragma unroll
        for (int ct = 0; ct < 2; ct++)
#pragma unroll
            for (int r = 0; r < 4; r++)
                hs[wave][tt * 16 + kg * 4 + r][ct * 16 + l15] = __float2half(acc[tt][ct][r]);
    __syncthreads();

    // coalesced H store: 2 iters x (16 rows x 64 B contiguous), 16 B/lane
#pragma unroll
    for (int it = 0; it < 2; it++) {
        int lr    = it * 16 + (lane >> 2);     // 0..31
        int chunk = lane & 3;                  // 16B chunk within 64B row
        int orow  = wbase + lr;
        if (orow < n) {
            uint4 v = *(const uint4*)&hs[wave][lr][chunk * 8];
            *(uint4*)(H + (size_t)orow * 32 + chunk * 8) = v;
        }
    }

    // coef (1 head): lanes 0..31, row = lane
    if (lane < 32) {
        int orow = wbase + lane;
        if (orow < n) {
            const __half2* hp = (const __half2*)&hs[wave][lane][0];
            float s = 0.f, d = 0.f;
#pragma unroll
            for (int c2 = 0; c2 < 16; c2++) {
                float2 v = __half22float2(hp[c2]);
                s += v.x * a_s[2 * c2] + v.y * a_s[2 * c2 + 1];
                d += v.x * a_d[2 * c2] + v.y * a_d[2 * c2 + 1];
            }
            as_out[orow] = s;
            ad_out[orow] = d;
        }
    }
}

// ---------------- fused online-softmax aggregation, fp16 gathers -----------

struct h4pack { __half2 a, b; };   // 4 halves = 8 B

__global__ __launch_bounds__(256)
void gat_fused_f16_kernel(const __half* __restrict__ Hm,
                          const float* __restrict__ as_,
                          const float* __restrict__ ad_,
                          const int* __restrict__ rowptr,
                          const int* __restrict__ csr,
                          const float* __restrict__ bias,
                          __half* __restrict__ out, int n) {
    constexpr int GS = 32;
    int t = threadIdx.x;
    int node = blockIdx.x * 8 + (t >> 5);
    if (node >= n) return;
    int tl = t & 31;
    int h  = tl >> 3;
    int k8 = tl & 7;
    const uint2* H8 = (const uint2*)Hm;     // 8 B = 4 halves per lane
    int e0 = rowptr[node], e1 = rowptr[node + 1];
    float ad_d = ad_[(size_t)node * 4 + h];

    int  ce  = e0 + k8;
    bool vA  = ce < e1;
    int  idxA = vA ? csr[ce] : 0;
    float asA = vA ? as_[(size_t)idxA * 4 + h] : 0.f;

    float m = -INFINITY, l = 0.f;
    float4 acc = make_float4(0.f, 0.f, 0.f, 0.f);

    for (int eb = e0; eb < e1; eb += 8) {
        uint2 u[8];
#pragma unroll
        for (int j = 0; j < 8; j++) {
            int src = __shfl(idxA, j, 8);
            u[j] = H8[(size_t)src * GS + tl];
        }

        int  ne  = eb + 8 + k8;
        bool vB  = ne < e1;
        int  idxB = vB ? csr[ne] : 0;
        float asB = vB ? as_[(size_t)idxB * 4 + h] : 0.f;

        float el = asA + ad_d;
        el = (el > 0.f) ? el : NEG_SLOPE * el;
        el = vA ? el : -INFINITY;

        float cm = el;
        cm = fmaxf(cm, __shfl_xor(cm, 1, 8));
        cm = fmaxf(cm, __shfl_xor(cm, 2, 8));
        cm = fmaxf(cm, __shfl_xor(cm, 4, 8));
        float m_new = fmaxf(m, cm);
        float scale = __expf(m - m_new);
        float p = vA ? __expf(el - m_new) : 0.f;

        float ps = p;
        ps += __shfl_xor(ps, 1, 8);
        ps += __shfl_xor(ps, 2, 8);
        ps += __shfl_xor(ps, 4, 8);
        l = l * scale + ps;
        acc.x *= scale; acc.y *= scale; acc.z *= scale; acc.w *= scale;
        m = m_new;

#pragma unroll
        for (int j = 0; j < 8; j++) {
            float pj  = __shfl(p, j, 8);
            float2 f01 = __half22float2(*(const __half2*)&u[j].x);
            float2 f23 = __half22float2(*(const __half2*)&u[j].y);
            acc.x += pj * f01.x; acc.y += pj * f01.y;
            acc.z += pj * f23.x; acc.w += pj * f23.y;
        }
        idxA = idxB; asA = asB; vA = vB;
    }

    float li = 1.f / (l + 1e-16f);
    float4 b4 = ((const float4*)bias)[tl];
    float4 o;
    o.x = fmaxf(acc.x * li + b4.x, 0.f);
    o.y = fmaxf(acc.y * li + b4.y, 0.f);
    o.z = fmaxf(acc.z * li + b4.z, 0.f);
    o.w = fmaxf(acc.w * li + b4.w, 0.f);
    h4pack po;
    po.a = __floats2half2_rn(o.x, o.y);
    po.b = __floats2half2_rn(o.z, o.w);
    ((h4pack*)out)[(size_t)node * 32 + tl] = po;
}

// ---------------- layer-2 fused: fp16 gathers + bias/relu + final linear ---

__global__ __launch_bounds__(256)
void gat_fused_l2_kernel(const __half* __restrict__ Hm,
                         const float* __restrict__ as_,
                         const float* __restrict__ ad_,
                         const int* __restrict__ rowptr,
                         const int* __restrict__ csr,
                         const float* __restrict__ bias,
                         const float* __restrict__ lw,
                         const float* __restrict__ lb,
                         float* __restrict__ out, int n) {
    int t = threadIdx.x;
    int node = blockIdx.x * 32 + (t >> 3);
    if (node >= n) return;
    int tl = t & 7;
    const uint2* H8 = (const uint2*)Hm;     // row = 8 uint2 (32 halves)
    int e0 = rowptr[node], e1 = rowptr[node + 1];
    float ad_d = ad_[node];

    int  ce  = e0 + tl;
    bool vA  = ce < e1;
    int  idxA = vA ? csr[ce] : 0;
    float asA = vA ? as_[idxA] : 0.f;

    float m = -INFINITY, l = 0.f;
    float4 acc = make_float4(0.f, 0.f, 0.f, 0.f);

    for (int eb = e0; eb < e1; eb += 8) {
        uint2 u[8];
#pragma unroll
        for (int j = 0; j < 8; j++) {
            int src = __shfl(idxA, j, 8);
            u[j] = H8[(size_t)src * 8 + tl];
        }

        int  ne  = eb + 8 + tl;
        bool vB  = ne < e1;
        int  idxB = vB ? csr[ne] : 0;
        float asB = vB ? as_[idxB] : 0.f;

        float el = asA + ad_d;
        el = (el > 0.f) ? el : NEG_SLOPE * el;
        el = vA ? el : -INFINITY;

        float cm = el;
        cm = fmaxf(cm, __shfl_xor(cm, 1, 8));
        cm = fmaxf(cm, __shfl_xor(cm, 2, 8));
        cm = fmaxf(cm, __shfl_xor(cm, 4, 8));
        float m_new = fmaxf(m, cm);
        float scale = __expf(m - m_new);
        float p = vA ? __expf(el - m_new) : 0.f;

        float ps = p;
        ps += __shfl_xor(ps, 1, 8);
        ps += __shfl_xor(ps, 2, 8);
        ps += __shfl_xor(ps, 4, 8);
        l = l * scale + ps;
        acc.x *= scale; acc.y *= scale; acc.z *= scale; acc.w *= scale;
        m = m_new;

#pragma unroll
        for (int j = 0; j < 8; j++) {
            float pj  = __shfl(p, j, 8);
            float2 f01 = __half22float2(*(const __half2*)&u[j].x);
            float2 f23 = __half22float2(*(const __half2*)&u[j].y);
            acc.x += pj * f01.x; acc.y += pj * f01.y;
            acc.z += pj * f23.x; acc.w += pj * f23.y;
        }
        idxA = idxB; asA = asB; vA = vB;
    }

    float li = 1.f / (l + 1e-16f);
    float4 b4 = ((const float4*)bias)[tl];
    float4 o;
    o.x = fmaxf(acc.x * li + b4.x, 0.f);
    o.y = fmaxf(acc.y * li + b4.y, 0.f);
    o.z = fmaxf(acc.z * li + b4.z, 0.f);
    o.w = fmaxf(acc.w * li + b4.w, 0.f);

    // fused final linear: lane tl computes classes tl + 8c (c = 0..4)
    float fin0 = lb[tl];
    float fin1 = lb[tl + 8];
    float fin2 = lb[tl + 16];
    float fin3 = lb[tl + 24];
    float fin4 = lb[tl + 32];
#pragma unroll
    for (int j = 0; j < 8; j++) {
        float vx = __shfl(o.x, j, 8);
        float vy = __shfl(o.y, j, 8);
        float vz = __shfl(o.z, j, 8);
        float vw = __shfl(o.w, j, 8);
        const float* l0 = lw + (size_t)(4 * j) * 40;   // rows 4j..4j+3 of lw[32,40]
#pragma unroll
        for (int c = 0; c < 5; c++) {
            int cls = tl + 8 * c;
            float v = vx * l0[cls] + vy * l0[40 + cls] + vz * l0[80 + cls] + vw * l0[120 + cls];
            if (c == 0) fin0 += v;
            else if (c == 1) fin1 += v;
            else if (c == 2) fin2 += v;
            else if (c == 3) fin3 += v;
            else fin4 += v;
        }
    }
    float* op = out + (size_t)node * 40;
    op[tl]      = fin0;
    op[tl + 8]  = fin1;
    op[tl + 16] = fin2;
    op[tl + 24] = fin3;
    op[tl + 32] = fin4;
}

// ---------------- launch ----------------

extern "C" void kernel_launch(void* const* d_in, const int* in_sizes, int n_in,
                              void* d_out, int out_size, void* d_ws, size_t ws_size,
                              hipStream_t stream) {
    const float* x   = (const float*)d_in[0];
    const int*   ei  = (const int*)d_in[1];
    const float* W0  = (const float*)d_in[2];
    const float* as0 = (const float*)d_in[3];
    const float* ad0 = (const float*)d_in[4];
    const float* b0  = (const float*)d_in[5];
    const float* W1  = (const float*)d_in[6];
    const float* as1 = (const float*)d_in[7];
    const float* ad1 = (const float*)d_in[8];
    const float* b1  = (const float*)d_in[9];
    const float* W2  = (const float*)d_in[10];
    const float* as2 = (const float*)d_in[11];
    const float* ad2 = (const float*)d_in[12];
    const float* b2  = (const float*)d_in[13];
    const float* lw  = (const float*)d_in[14];
    const float* lb  = (const float*)d_in[15];
    float* out = (float*)d_out;

    const int n    = in_sizes[0] / 128;   // 100000 (= 32 * 3125)
    const int eraw = in_sizes[1] / 2;     // 1600000
    const int etot = eraw + n;
    const int nb   = (n + 1023) / 1024;

    char* wsp = (char*)d_ws;
    size_t off = 0;
    auto alloc = [&](size_t bytes) -> void* {
        void* p = wsp + off;
        off += (bytes + 255) & ~(size_t)255;
        return p;
    };
    __half* h16    = (__half*)alloc((size_t)n * 128 * 2);  // per-layer h table
    __half* buf16  = (__half*)alloc((size_t)n * 128 * 2);  // inter-layer activations
    __half* h2     = (__half*)alloc((size_t)n * 32 * 2);   // layer-2 h table
    __half* Wp0    = (__half*)alloc((size_t)128 * 128 * 2);
    __half* Wp1    = (__half*)alloc((size_t)128 * 128 * 2);
    __half* Wp2    = (__half*)alloc((size_t)128 * 32 * 2);
    float*  asb    = (float*)alloc((size_t)n * 4 * 4);
    float*  adb    = (float*)alloc((size_t)n * 4 * 4);
    int*    deg    = (int*)alloc((size_t)n * 4);
    int*    rank   = (int*)alloc((size_t)etot * 4);
    int*    rowptr = (int*)alloc((size_t)(n + 1) * 4);
    int*    csr    = (int*)alloc((size_t)etot * 4);
    int*    bsum   = (int*)alloc((size_t)nb * 4);
    int*    boffs  = (int*)alloc((size_t)nb * 4);

    // --- CSR build (single atomic pass) + W pre-pack ---
    zero1_kernel<<<(n + 255) / 256, 256, 0, stream>>>(deg, n);
    count_rank_kernel<<<(etot + 255) / 256, 256, 0, stream>>>(ei, eraw, n, deg, rank);
    wpack_f16_kernel<128><<<64, 256, 0, stream>>>(W0, Wp0);
    wpack_f16_kernel<128><<<64, 256, 0, stream>>>(W1, Wp1);
    wpack_f16_kernel<32><<<16, 256, 0, stream>>>(W2, Wp2);
    scan_local_kernel<<<nb, 1024, 0, stream>>>(deg, rowptr, bsum, n);
    scan_sums_kernel<<<1, 128, 0, stream>>>(bsum, boffs, nb);
    scan_add_kernel<<<(n + 255) / 256, 256, 0, stream>>>(rowptr, boffs, n, etot);
    scatter2_kernel<<<(etot + 255) / 256, 256, 0, stream>>>(ei, rank, eraw, n, rowptr, csr);

    const int gblocks = (n + 127) / 128;

    // --- layer 0: 128 -> 4x32, concat ---
    gemm_mfma_coef_kernel<true><<<gblocks, 256, 0, stream>>>(x, Wp0, as0, ad0, h16, asb, adb, n);
    gat_fused_f16_kernel<<<(n + 7) / 8, 256, 0, stream>>>(h16, asb, adb, rowptr, csr, b0, buf16, n);

    // --- layer 1: 128 -> 4x32, concat ---
    gemm_mfma_coef_kernel<false><<<gblocks, 256, 0, stream>>>(buf16, Wp1, as1, ad1, h16, asb, adb, n);
    gat_fused_f16_kernel<<<(n + 7) / 8, 256, 0, stream>>>(h16, asb, adb, rowptr, csr, b1, buf16, n);

    // --- layer 2: 128 -> 1x32 (MFMA + fused coef), + fused final linear ---
    gemm_mfma_l2_kernel<<<gblocks, 256, 0, stream>>>(buf16, Wp2, as2, ad2, h2, asb, adb, n);
    gat_fused_l2_kernel<<<(n + 31) / 32, 256, 0, stream>>>(h2, asb, adb, rowptr, csr, b2, lw, lb, out, n);
}

// Round 10
// 461.208 us; speedup vs baseline: 1.5269x; 1.0120x over previous
//
#include <hip/hip_runtime.h>
#include <hip/hip_bf16.h>
#include <hip/hip_fp16.h>
#include <math.h>

// ---------------------------------------------------------------------------
// GAT (3 layers, heads=4/4/1, hid=32) + final linear.
// R21: swapped-operand MFMA GEMM (layers 0/1). Computing D = W^T x X^T (=C^T)
//      puts 4 CONSECUTIVE H-columns of one node in each lane's 4 acc regs:
//      H store = packed 8-B store from registers (16 instrs), attn-coef =
//      local 8-elem dot + 2 shfl_xor. Kills R20's LDS transpose (64 scalar
//      ds_write_b16 + barrier + LDS re-reads per thread). Wp packing and X
//      load addresses unchanged (A/B fragment layouts are symmetric).
//      Everything else identical to R20.
// ---------------------------------------------------------------------------

#define NEG_SLOPE 0.2f

typedef __attribute__((ext_vector_type(8))) _Float16 f16x8;
typedef __attribute__((ext_vector_type(4))) float    f32x4;

struct h4pack { __half2 a, b; };   // 4 halves = 8 B

// ---------------- CSR build ----------------

__global__ void zero1_kernel(int* __restrict__ a, int n) {
    int i = blockIdx.x * blockDim.x + threadIdx.x;
    if (i < n) a[i] = 0;
}

__global__ void count_rank_kernel(const int* __restrict__ ei, int eraw, int n,
                                  int* __restrict__ deg, int* __restrict__ rank) {
    int i = blockIdx.x * blockDim.x + threadIdx.x;
    int etot = eraw + n;
    if (i >= etot) return;
    int dst = (i < eraw) ? ei[eraw + i] : (i - eraw);
    rank[i] = atomicAdd(&deg[dst], 1);
}

__global__ __launch_bounds__(1024)
void scan_local_kernel(const int* __restrict__ deg, int* __restrict__ rowptr,
                       int* __restrict__ bsum, int n) {
    __shared__ int buf[1024];
    int tid = threadIdx.x;
    int i = blockIdx.x * 1024 + tid;
    int v = (i < n) ? deg[i] : 0;
    buf[tid] = v;
    __syncthreads();
    for (int off = 1; off < 1024; off <<= 1) {
        int t = (tid >= off) ? buf[tid - off] : 0;
        __syncthreads();
        buf[tid] += t;
        __syncthreads();
    }
    if (i < n) rowptr[i] = buf[tid] - v;
    if (tid == 1023) bsum[blockIdx.x] = buf[1023];
}

__global__ __launch_bounds__(128)
void scan_sums_kernel(const int* __restrict__ bsum, int* __restrict__ boffs, int nb) {
    __shared__ int buf[128];
    int tid = threadIdx.x;
    int v = (tid < nb) ? bsum[tid] : 0;
    buf[tid] = v;
    __syncthreads();
    for (int off = 1; off < 128; off <<= 1) {
        int t = (tid >= off) ? buf[tid - off] : 0;
        __syncthreads();
        buf[tid] += t;
        __syncthreads();
    }
    if (tid < nb) boffs[tid] = buf[tid] - v;
}

__global__ void scan_add_kernel(int* __restrict__ rowptr, const int* __restrict__ boffs,
                                int n, int etot) {
    int i = blockIdx.x * blockDim.x + threadIdx.x;
    if (i < n) rowptr[i] += boffs[i >> 10];
    if (i == 0) rowptr[n] = etot;
}

__global__ void scatter2_kernel(const int* __restrict__ ei, const int* __restrict__ rank,
                                int eraw, int n, const int* __restrict__ rowptr,
                                int* __restrict__ csr_src) {
    int i = blockIdx.x * blockDim.x + threadIdx.x;
    int etot = eraw + n;
    if (i >= etot) return;
    int src, dst;
    if (i < eraw) { src = ei[i]; dst = ei[eraw + i]; }
    else          { src = i - eraw; dst = src; }
    csr_src[rowptr[dst] + rank[i]] = src;
}

// ---------------- W -> fp16 packed in MFMA fragment order ------------------
// OUTC = output cols (128 or 32). Wp[((ct*4+ks)*64+lane)*8+j] =
//   W[(ks*32 + (lane>>4)*8 + j)*OUTC + ct*16 + (lane&15)]

template <int OUTC>
__global__ void wpack_f16_kernel(const float* __restrict__ W, __half* __restrict__ Wp) {
    int i = blockIdx.x * blockDim.x + threadIdx.x;   // 128*OUTC
    int j    = i & 7;
    int lane = (i >> 3) & 63;
    int ks   = (i >> 9) & 3;
    int ct   = i >> 11;
    int k = ks * 32 + (lane >> 4) * 8 + j;
    int c = ct * 16 + (lane & 15);
    Wp[i] = __float2half(W[k * OUTC + c]);
}

// ---------------- swapped-operand MFMA GEMM + fused attn-coef (L0/L1) ------
// Block = 256 threads = 4 waves. Wave handles 32 nodes (2 tiles of 16),
// 8 col-tiles, K=128 in 4 steps -> 64 MFMA per wave.
// D = W^T x X^T: lane (l15,kg), reg r holds H[node=tile+l15][ct*16+kg*4+r].

template <bool F32IN>
__global__ __launch_bounds__(256)
void gemm_mfma_coef_kernel(const void* __restrict__ Xv, const __half* __restrict__ Wp,
                           const float* __restrict__ a_s, const float* __restrict__ a_d,
                           __half* __restrict__ H, float* __restrict__ as_out,
                           float* __restrict__ ad_out, int n) {
    int t = threadIdx.x;
    int lane = t & 63;
    int wave = t >> 6;
    int l15 = lane & 15;
    int kg  = lane >> 4;                 // 0..3
    int wbase = blockIdx.x * 128 + wave * 32;

    int node0 = wbase + l15;
    int node1 = wbase + 16 + l15;
    int n0c = (node0 < n) ? node0 : 0;
    int n1c = (node1 < n) ? node1 : 0;

    f32x4 acc[2][8];
#pragma unroll
    for (int tt = 0; tt < 2; tt++)
#pragma unroll
        for (int i = 0; i < 8; i++) acc[tt][i] = (f32x4){0.f, 0.f, 0.f, 0.f};

#pragma unroll
    for (int ks = 0; ks < 4; ks++) {
        f16x8 b0, b1;                    // X fragments (B operand: X^T)
        if constexpr (F32IN) {
            const float* X = (const float*)Xv;
            const float* p0 = X + (size_t)n0c * 128 + kg * 8 + ks * 32;
            const float* p1 = X + (size_t)n1c * 128 + kg * 8 + ks * 32;
            float4 x0 = *(const float4*)(p0), x1 = *(const float4*)(p0 + 4);
            b0[0] = (_Float16)x0.x; b0[1] = (_Float16)x0.y; b0[2] = (_Float16)x0.z; b0[3] = (_Float16)x0.w;
            b0[4] = (_Float16)x1.x; b0[5] = (_Float16)x1.y; b0[6] = (_Float16)x1.z; b0[7] = (_Float16)x1.w;
            float4 y0 = *(const float4*)(p1), y1 = *(const float4*)(p1 + 4);
            b1[0] = (_Float16)y0.x; b1[1] = (_Float16)y0.y; b1[2] = (_Float16)y0.z; b1[3] = (_Float16)y0.w;
            b1[4] = (_Float16)y1.x; b1[5] = (_Float16)y1.y; b1[6] = (_Float16)y1.z; b1[7] = (_Float16)y1.w;
        } else {
            const __half* X = (const __half*)Xv;
            b0 = *(const f16x8*)(X + (size_t)n0c * 128 + kg * 8 + ks * 32);
            b1 = *(const f16x8*)(X + (size_t)n1c * 128 + kg * 8 + ks * 32);
        }
#pragma unroll
        for (int ct = 0; ct < 8; ct++) {
            f16x8 a = *(const f16x8*)(Wp + (size_t)((ct * 4 + ks) * 64 + lane) * 8);
            acc[0][ct] = __builtin_amdgcn_mfma_f32_16x16x32_f16(a, b0, acc[0][ct], 0, 0, 0);
            acc[1][ct] = __builtin_amdgcn_mfma_f32_16x16x32_f16(a, b1, acc[1][ct], 0, 0, 0);
        }
    }

    // packed 8-B H store straight from registers
#pragma unroll
    for (int tt = 0; tt < 2; tt++) {
        int node = wbase + tt * 16 + l15;
        if (node < n) {
#pragma unroll
            for (int ct = 0; ct < 8; ct++) {
                h4pack p;
                p.a = __floats2half2_rn(acc[tt][ct][0], acc[tt][ct][1]);
                p.b = __floats2half2_rn(acc[tt][ct][2], acc[tt][ct][3]);
                *(h4pack*)(H + (size_t)node * 128 + ct * 16 + kg * 4) = p;
            }
        }
    }

    // fused attn-coef: lane locally dots its 8 in-head values, then reduces
    // across the 4 kg-lanes (shfl_xor 16, 32).
#pragma unroll
    for (int tt = 0; tt < 2; tt++) {
        int node = wbase + tt * 16 + l15;
#pragma unroll
        for (int h = 0; h < 4; h++) {
            float s = 0.f, d = 0.f;
#pragma unroll
            for (int q = 0; q < 2; q++) {
                int ct = 2 * h + q;
#pragma unroll
                for (int r = 0; r < 4; r++) {
                    int c = q * 16 + kg * 4 + r;       // channel within head
                    float v = acc[tt][ct][r];
                    s += v * a_s[h * 32 + c];
                    d += v * a_d[h * 32 + c];
                }
            }
            s += __shfl_xor(s, 16); s += __shfl_xor(s, 32);
            d += __shfl_xor(d, 16); d += __shfl_xor(d, 32);
            if (kg == 0 && node < n) {
                as_out[(size_t)node * 4 + h] = s;
                ad_out[(size_t)node * 4 + h] = d;
            }
        }
    }
}

// ---------------- layer-2 MFMA GEMM + fused coef (unchanged from R20) ------

__global__ __launch_bounds__(256)
void gemm_mfma_l2_kernel(const __half* __restrict__ X, const __half* __restrict__ Wp,
                         const float* __restrict__ a_s, const float* __restrict__ a_d,
                         __half* __restrict__ H, float* __restrict__ as_out,
                         float* __restrict__ ad_out, int n) {
    __shared__ __half hs[4][32][40];    // 10,240 B; 80 B/row: 16B-aligned
    int t = threadIdx.x;
    int wave = t >> 6, lane = t & 63;
    int l15 = lane & 15;
    int kg  = lane >> 4;
    int wbase = blockIdx.x * 128 + wave * 32;

    int row0 = wbase + l15;
    int row1 = wbase + 16 + l15;
    int r0c = (row0 < n) ? row0 : 0;
    int r1c = (row1 < n) ? row1 : 0;

    f32x4 acc[2][2];
#pragma unroll
    for (int tt = 0; tt < 2; tt++)
#pragma unroll
        for (int i = 0; i < 2; i++) acc[tt][i] = (f32x4){0.f, 0.f, 0.f, 0.f};

#pragma unroll
    for (int ks = 0; ks < 4; ks++) {
        f16x8 a0 = *(const f16x8*)(X + (size_t)r0c * 128 + kg * 8 + ks * 32);
        f16x8 a1 = *(const f16x8*)(X + (size_t)r1c * 128 + kg * 8 + ks * 32);
#pragma unroll
        for (int ct = 0; ct < 2; ct++) {
            f16x8 b = *(const f16x8*)(Wp + (size_t)((ct * 4 + ks) * 64 + lane) * 8);
            acc[0][ct] = __builtin_amdgcn_mfma_f32_16x16x32_f16(a0, b, acc[0][ct], 0, 0, 0);
            acc[1][ct] = __builtin_amdgcn_mfma_f32_16x16x32_f16(a1, b, acc[1][ct], 0, 0, 0);
        }
    }

#pragma unroll
    for (int tt = 0; tt < 2; tt++)
#pragma unroll
        for (int ct = 0; ct < 2; ct++)
#pragma unroll
            for (int r = 0; r < 4; r++)
                hs[wave][tt * 16 + kg * 4 + r][ct * 16 + l15] = __float2half(acc[tt][ct][r]);
    __syncthreads();

    // coalesced H store: 2 iters x (16 rows x 64 B contiguous), 16 B/lane
#pragma unroll
    for (int it = 0; it < 2; it++) {
        int lr    = it * 16 + (lane >> 2);     // 0..31
        int chunk = lane & 3;                  // 16B chunk within 64B row
        int orow  = wbase + lr;
        if (orow < n) {
            uint4 v = *(const uint4*)&hs[wave][lr][chunk * 8];
            *(uint4*)(H + (size_t)orow * 32 + chunk * 8) = v;
        }
    }

    // coef (1 head): lanes 0..31, row = lane
    if (lane < 32) {
        int orow = wbase + lane;
        if (orow < n) {
            const __half2* hp = (const __half2*)&hs[wave][lane][0];
            float s = 0.f, d = 0.f;
#pragma unroll
            for (int c2 = 0; c2 < 16; c2++) {
                float2 v = __half22float2(hp[c2]);
                s += v.x * a_s[2 * c2] + v.y * a_s[2 * c2 + 1];
                d += v.x * a_d[2 * c2] + v.y * a_d[2 * c2 + 1];
            }
            as_out[orow] = s;
            ad_out[orow] = d;
        }
    }
}

// ---------------- fused online-softmax aggregation, fp16 gathers -----------

__global__ __launch_bounds__(256)
void gat_fused_f16_kernel(const __half* __restrict__ Hm,
                          const float* __restrict__ as_,
                          const float* __restrict__ ad_,
                          const int* __restrict__ rowptr,
                          const int* __restrict__ csr,
                          const float* __restrict__ bias,
                          __half* __restrict__ out, int n) {
    constexpr int GS = 32;
    int t = threadIdx.x;
    int node = blockIdx.x * 8 + (t >> 5);
    if (node >= n) return;
    int tl = t & 31;
    int h  = tl >> 3;
    int k8 = tl & 7;
    const uint2* H8 = (const uint2*)Hm;     // 8 B = 4 halves per lane
    int e0 = rowptr[node], e1 = rowptr[node + 1];
    float ad_d = ad_[(size_t)node * 4 + h];

    int  ce  = e0 + k8;
    bool vA  = ce < e1;
    int  idxA = vA ? csr[ce] : 0;
    float asA = vA ? as_[(size_t)idxA * 4 + h] : 0.f;

    float m = -INFINITY, l = 0.f;
    float4 acc = make_float4(0.f, 0.f, 0.f, 0.f);

    for (int eb = e0; eb < e1; eb += 8) {
        uint2 u[8];
#pragma unroll
        for (int j = 0; j < 8; j++) {
            int src = __shfl(idxA, j, 8);
            u[j] = H8[(size_t)src * GS + tl];
        }

        int  ne  = eb + 8 + k8;
        bool vB  = ne < e1;
        int  idxB = vB ? csr[ne] : 0;
        float asB = vB ? as_[(size_t)idxB * 4 + h] : 0.f;

        float el = asA + ad_d;
        el = (el > 0.f) ? el : NEG_SLOPE * el;
        el = vA ? el : -INFINITY;

        float cm = el;
        cm = fmaxf(cm, __shfl_xor(cm, 1, 8));
        cm = fmaxf(cm, __shfl_xor(cm, 2, 8));
        cm = fmaxf(cm, __shfl_xor(cm, 4, 8));
        float m_new = fmaxf(m, cm);
        float scale = __expf(m - m_new);
        float p = vA ? __expf(el - m_new) : 0.f;

        float ps = p;
        ps += __shfl_xor(ps, 1, 8);
        ps += __shfl_xor(ps, 2, 8);
        ps += __shfl_xor(ps, 4, 8);
        l = l * scale + ps;
        acc.x *= scale; acc.y *= scale; acc.z *= scale; acc.w *= scale;
        m = m_new;

#pragma unroll
        for (int j = 0; j < 8; j++) {
            float pj  = __shfl(p, j, 8);
            float2 f01 = __half22float2(*(const __half2*)&u[j].x);
            float2 f23 = __half22float2(*(const __half2*)&u[j].y);
            acc.x += pj * f01.x; acc.y += pj * f01.y;
            acc.z += pj * f23.x; acc.w += pj * f23.y;
        }
        idxA = idxB; asA = asB; vA = vB;
    }

    float li = 1.f / (l + 1e-16f);
    float4 b4 = ((const float4*)bias)[tl];
    float4 o;
    o.x = fmaxf(acc.x * li + b4.x, 0.f);
    o.y = fmaxf(acc.y * li + b4.y, 0.f);
    o.z = fmaxf(acc.z * li + b4.z, 0.f);
    o.w = fmaxf(acc.w * li + b4.w, 0.f);
    h4pack po;
    po.a = __floats2half2_rn(o.x, o.y);
    po.b = __floats2half2_rn(o.z, o.w);
    ((h4pack*)out)[(size_t)node * 32 + tl] = po;
}

// ---------------- layer-2 fused: fp16 gathers + bias/relu + final linear ---

__global__ __launch_bounds__(256)
void gat_fused_l2_kernel(const __half* __restrict__ Hm,
                         const float* __restrict__ as_,
                         const float* __restrict__ ad_,
                         const int* __restrict__ rowptr,
                         const int* __restrict__ csr,
                         const float* __restrict__ bias,
                         const float* __restrict__ lw,
                         const float* __restrict__ lb,
                         float* __restrict__ out, int n) {
    int t = threadIdx.x;
    int node = blockIdx.x * 32 + (t >> 3);
    if (node >= n) return;
    int tl = t & 7;
    const uint2* H8 = (const uint2*)Hm;     // row = 8 uint2 (32 halves)
    int e0 = rowptr[node], e1 = rowptr[node + 1];
    float ad_d = ad_[node];

    int  ce  = e0 + tl;
    bool vA  = ce < e1;
    int  idxA = vA ? csr[ce] : 0;
    float asA = vA ? as_[idxA] : 0.f;

    float m = -INFINITY, l = 0.f;
    float4 acc = make_float4(0.f, 0.f, 0.f, 0.f);

    for (int eb = e0; eb < e1; eb += 8) {
        uint2 u[8];
#pragma unroll
        for (int j = 0; j < 8; j++) {
            int src = __shfl(idxA, j, 8);
            u[j] = H8[(size_t)src * 8 + tl];
        }

        int  ne  = eb + 8 + tl;
        bool vB  = ne < e1;
        int  idxB = vB ? csr[ne] : 0;
        float asB = vB ? as_[idxB] : 0.f;

        float el = asA + ad_d;
        el = (el > 0.f) ? el : NEG_SLOPE * el;
        el = vA ? el : -INFINITY;

        float cm = el;
        cm = fmaxf(cm, __shfl_xor(cm, 1, 8));
        cm = fmaxf(cm, __shfl_xor(cm, 2, 8));
        cm = fmaxf(cm, __shfl_xor(cm, 4, 8));
        float m_new = fmaxf(m, cm);
        float scale = __expf(m - m_new);
        float p = vA ? __expf(el - m_new) : 0.f;

        float ps = p;
        ps += __shfl_xor(ps, 1, 8);
        ps += __shfl_xor(ps, 2, 8);
        ps += __shfl_xor(ps, 4, 8);
        l = l * scale + ps;
        acc.x *= scale; acc.y *= scale; acc.z *= scale; acc.w *= scale;
        m = m_new;

#pragma unroll
        for (int j = 0; j < 8; j++) {
            float pj  = __shfl(p, j, 8);
            float2 f01 = __half22float2(*(const __half2*)&u[j].x);
            float2 f23 = __half22float2(*(const __half2*)&u[j].y);
            acc.x += pj * f01.x; acc.y += pj * f01.y;
            acc.z += pj * f23.x; acc.w += pj * f23.y;
        }
        idxA = idxB; asA = asB; vA = vB;
    }

    float li = 1.f / (l + 1e-16f);
    float4 b4 = ((const float4*)bias)[tl];
    float4 o;
    o.x = fmaxf(acc.x * li + b4.x, 0.f);
    o.y = fmaxf(acc.y * li + b4.y, 0.f);
    o.z = fmaxf(acc.z * li + b4.z, 0.f);
    o.w = fmaxf(acc.w * li + b4.w, 0.f);

    // fused final linear: lane tl computes classes tl + 8c (c = 0..4)
    float fin0 = lb[tl];
    float fin1 = lb[tl + 8];
    float fin2 = lb[tl + 16];
    float fin3 = lb[tl + 24];
    float fin4 = lb[tl + 32];
#pragma unroll
    for (int j = 0; j < 8; j++) {
        float vx = __shfl(o.x, j, 8);
        float vy = __shfl(o.y, j, 8);
        float vz = __shfl(o.z, j, 8);
        float vw = __shfl(o.w, j, 8);
        const float* l0 = lw + (size_t)(4 * j) * 40;   // rows 4j..4j+3 of lw[32,40]
#pragma unroll
        for (int c = 0; c < 5; c++) {
            int cls = tl + 8 * c;
            float v = vx * l0[cls] + vy * l0[40 + cls] + vz * l0[80 + cls] + vw * l0[120 + cls];
            if (c == 0) fin0 += v;
            else if (c == 1) fin1 += v;
            else if (c == 2) fin2 += v;
            else if (c == 3) fin3 += v;
            else fin4 += v;
        }
    }
    float* op = out + (size_t)node * 40;
    op[tl]      = fin0;
    op[tl + 8]  = fin1;
    op[tl + 16] = fin2;
    op[tl + 24] = fin3;
    op[tl + 32] = fin4;
}

// ---------------- launch ----------------

extern "C" void kernel_launch(void* const* d_in, const int* in_sizes, int n_in,
                              void* d_out, int out_size, void* d_ws, size_t ws_size,
                              hipStream_t stream) {
    const float* x   = (const float*)d_in[0];
    const int*   ei  = (const int*)d_in[1];
    const float* W0  = (const float*)d_in[2];
    const float* as0 = (const float*)d_in[3];
    const float* ad0 = (const float*)d_in[4];
    const float* b0  = (const float*)d_in[5];
    const float* W1  = (const float*)d_in[6];
    const float* as1 = (const float*)d_in[7];
    const float* ad1 = (const float*)d_in[8];
    const float* b1  = (const float*)d_in[9];
    const float* W2  = (const float*)d_in[10];
    const float* as2 = (const float*)d_in[11];
    const float* ad2 = (const float*)d_in[12];
    const float* b2  = (const float*)d_in[13];
    const float* lw  = (const float*)d_in[14];
    const float* lb  = (const float*)d_in[15];
    float* out = (float*)d_out;

    const int n    = in_sizes[0] / 128;   // 100000 (= 32 * 3125)
    const int eraw = in_sizes[1] / 2;     // 1600000
    const int etot = eraw + n;
    const int nb   = (n + 1023) / 1024;

    char* wsp = (char*)d_ws;
    size_t off = 0;
    auto alloc = [&](size_t bytes) -> void* {
        void* p = wsp + off;
        off += (bytes + 255) & ~(size_t)255;
        return p;
    };
    __half* h16    = (__half*)alloc((size_t)n * 128 * 2);  // per-layer h table
    __half* buf16  = (__half*)alloc((size_t)n * 128 * 2);  // inter-layer activations
    __half* h2     = (__half*)alloc((size_t)n * 32 * 2);   // layer-2 h table
    __half* Wp0    = (__half*)alloc((size_t)128 * 128 * 2);
    __half* Wp1    = (__half*)alloc((size_t)128 * 128 * 2);
    __half* Wp2    = (__half*)alloc((size_t)128 * 32 * 2);
    float*  asb    = (float*)alloc((size_t)n * 4 * 4);
    float*  adb    = (float*)alloc((size_t)n * 4 * 4);
    int*    deg    = (int*)alloc((size_t)n * 4);
    int*    rank   = (int*)alloc((size_t)etot * 4);
    int*    rowptr = (int*)alloc((size_t)(n + 1) * 4);
    int*    csr    = (int*)alloc((size_t)etot * 4);
    int*    bsum   = (int*)alloc((size_t)nb * 4);
    int*    boffs  = (int*)alloc((size_t)nb * 4);

    // --- CSR build (single atomic pass) + W pre-pack ---
    zero1_kernel<<<(n + 255) / 256, 256, 0, stream>>>(deg, n);
    count_rank_kernel<<<(etot + 255) / 256, 256, 0, stream>>>(ei, eraw, n, deg, rank);
    wpack_f16_kernel<128><<<64, 256, 0, stream>>>(W0, Wp0);
    wpack_f16_kernel<128><<<64, 256, 0, stream>>>(W1, Wp1);
    wpack_f16_kernel<32><<<16, 256, 0, stream>>>(W2, Wp2);
    scan_local_kernel<<<nb, 1024, 0, stream>>>(deg, rowptr, bsum, n);
    scan_sums_kernel<<<1, 128, 0, stream>>>(bsum, boffs, nb);
    scan_add_kernel<<<(n + 255) / 256, 256, 0, stream>>>(rowptr, boffs, n, etot);
    scatter2_kernel<<<(etot + 255) / 256, 256, 0, stream>>>(ei, rank, eraw, n, rowptr, csr);

    const int gblocks = (n + 127) / 128;

    // --- layer 0: 128 -> 4x32, concat ---
    gemm_mfma_coef_kernel<true><<<gblocks, 256, 0, stream>>>(x, Wp0, as0, ad0, h16, asb, adb, n);
    gat_fused_f16_kernel<<<(n + 7) / 8, 256, 0, stream>>>(h16, asb, adb, rowptr, csr, b0, buf16, n);

    // --- layer 1: 128 -> 4x32, concat ---
    gemm_mfma_coef_kernel<false><<<gblocks, 256, 0, stream>>>(buf16, Wp1, as1, ad1, h16, asb, adb, n);
    gat_fused_f16_kernel<<<(n + 7) / 8, 256, 0, stream>>>(h16, asb, adb, rowptr, csr, b1, buf16, n);

    // --- layer 2: 128 -> 1x32 (MFMA + fused coef), + fused final linear ---
    gemm_mfma_l2_kernel<<<gblocks, 256, 0, stream>>>(buf16, Wp2, as2, ad2, h2, asb, adb, n);
    gat_fused_l2_kernel<<<(n + 31) / 32, 256, 0, stream>>>(h2, asb, adb, rowptr, csr, b2, lw, lb, out, n);
}